// Round 13
// baseline (301.012 us; speedup 1.0000x reference)
//
#include <hip/hip_runtime.h>
#include <hip/hip_bf16.h>

#define T_TOK 4096
#define H_DIM 1024
#define DFF_D 2048
#define E_NUM 8
#define K_TOP 2
#define MAXJOBS64 136
#define MAXJOBS128 72

typedef __attribute__((ext_vector_type(8))) short s16x8;
typedef __attribute__((ext_vector_type(4))) float f32x4;

__device__ __forceinline__ ushort f2bf(float f) {
    unsigned u = __float_as_uint(f);
    u = (u + 0x7FFFu + ((u >> 16) & 1u)) >> 16;  // RNE
    return (ushort)u;
}

__device__ __forceinline__ float bf2f(short s) {
    return __uint_as_float(((unsigned)(ushort)s) << 16);
}

__device__ __forceinline__ void glds16(const ushort* g, ushort* l) {
    __builtin_amdgcn_global_load_lds(
        (const __attribute__((address_space(1))) unsigned*)g,
        (__attribute__((address_space(3))) unsigned*)l, 16, 0, 0);
}

// swizzled LDS fragment read: tile stored [rows][64] bf16 (128B rows),
// source staged with matching inverse swizzle on the global address.
__device__ __forceinline__ s16x8 lds_frag(const ushort* base, int row, int bytecol) {
    int byte = row * 128 + (bytecol ^ ((row & 7) << 4));
    return *(const s16x8*)((const char*)base + byte);
}

__device__ __forceinline__ void cvt8(const float* p, ushort* dst, size_t i) {
    float4 a = ((const float4*)(p + i * 8))[0];
    float4 b = ((const float4*)(p + i * 8))[1];
    union { ushort us[8]; uint4 q; } o;
    o.us[0] = f2bf(a.x); o.us[1] = f2bf(a.y); o.us[2] = f2bf(a.z); o.us[3] = f2bf(a.w);
    o.us[4] = f2bf(b.x); o.us[5] = f2bf(b.y); o.us[6] = f2bf(b.z); o.us[7] = f2bf(b.w);
    ((uint4*)dst)[i] = o.q;
}

#define PHASE_BARRIER() do { \
    __builtin_amdgcn_sched_barrier(0); \
    __builtin_amdgcn_s_barrier(); \
    __builtin_amdgcn_sched_barrier(0); } while (0)

// ---------------- fp32 -> bf16 bulk converts ----------------
__global__ __launch_bounds__(256) void cvt_kernel(
    const float* __restrict__ in, ushort* __restrict__ out, int n8)
{
    int i = blockIdx.x * blockDim.x + threadIdx.x;
    const int stride = gridDim.x * blockDim.x;
    for (; i < n8; i += stride) cvt8(in, out, i);
}

// W1,W2[,W3] -> bf16 (W3 optional, ws-size dependent)
__global__ __launch_bounds__(256) void cvtW_kernel(
    const float* __restrict__ W1, ushort* __restrict__ w1bf,
    const float* __restrict__ W2, ushort* __restrict__ w2bf,
    const float* __restrict__ W3, ushort* __restrict__ w3bf)
{
    const int nW = E_NUM * DFF_D * H_DIM / 8;   // 2,097,152 chunks each
    const int total = (W3 != nullptr) ? 3 * nW : 2 * nW;
    int i = blockIdx.x * blockDim.x + threadIdx.x;
    const int stride = gridDim.x * blockDim.x;
    for (; i < total; i += stride) {
        if (i < nW)            cvt8(W1, w1bf, i);
        else if (i < 2 * nW)   cvt8(W2, w2bf, i - nW);
        else                   cvt8(W3, w3bf, i - 2 * nW);
    }
}

// ---------------- gate: scores + top-2 + x->bf16 (no global atomics) ----------------
__global__ __launch_bounds__(256) void gate_kernel(
    const float* __restrict__ x, const float* __restrict__ Wg,
    int* __restrict__ topi_packed, float* __restrict__ wt_slot,
    ushort* __restrict__ xbf)
{
    const int t = blockIdx.x * 4 + (threadIdx.x >> 6);
    const int lane = threadIdx.x & 63;
    const float* xr = x + (size_t)t * H_DIM;
    float xv[16];
    #pragma unroll
    for (int j = 0; j < 16; ++j) xv[j] = xr[j * 64 + lane];

    ushort* xo = xbf + (size_t)t * H_DIM;
    #pragma unroll
    for (int j = 0; j < 16; ++j) xo[j * 64 + lane] = f2bf(xv[j]);

    float score[E_NUM];
    #pragma unroll
    for (int e = 0; e < E_NUM; ++e) {
        const float* wr = Wg + e * H_DIM;
        float p = 0.f;
        #pragma unroll
        for (int j = 0; j < 16; ++j) p += xv[j] * wr[j * 64 + lane];
        #pragma unroll
        for (int s = 32; s >= 1; s >>= 1) p += __shfl_xor(p, s, 64);
        score[e] = p;
    }
    if (lane == 0) {
        int i0 = 0;
        #pragma unroll
        for (int e = 1; e < E_NUM; ++e) if (score[e] > score[i0]) i0 = e;
        int i1 = (i0 == 0) ? 1 : 0;
        #pragma unroll
        for (int e = 0; e < E_NUM; ++e)
            if (e != i0 && score[e] > score[i1]) i1 = e;
        float e1 = expf(score[i1] - score[i0]);
        float w0 = 1.f / (1.f + e1);
        float w1 = e1 / (1.f + e1);
        topi_packed[t] = i0 | (i1 << 8);
        wt_slot[t * K_TOP + 0] = w0;
        wt_slot[t * K_TOP + 1] = w1;
    }
}

// ---------------- per-expert token lists via LDS atomics ----------------
__global__ __launch_bounds__(256) void build_lists(
    const int* __restrict__ topi_packed,
    int* __restrict__ cnt, int* __restrict__ tok_list, int* __restrict__ slot_list)
{
    const int e = blockIdx.x;
    __shared__ int lcnt;
    if (threadIdx.x == 0) lcnt = 0;
    __syncthreads();
    for (int t = threadIdx.x; t < T_TOK; t += 256) {
        int pk = topi_packed[t];
        int i0 = pk & 0xff;
        int i1 = (pk >> 8) & 0xff;
        if (i0 == e) {
            int p = atomicAdd(&lcnt, 1);
            tok_list[e * T_TOK + p] = t;
            slot_list[e * T_TOK + p] = t * K_TOP + 0;
        }
        if (i1 == e) {
            int p = atomicAdd(&lcnt, 1);
            tok_list[e * T_TOK + p] = t;
            slot_list[e * T_TOK + p] = t * K_TOP + 1;
        }
    }
    __syncthreads();
    if (threadIdx.x == 0) cnt[e] = lcnt;
}

// ---------------- dense (e, mtile) job lists: BM=64 and BM=128 ----------------
__global__ void build_jobs(const int* __restrict__ cnt,
                           int* __restrict__ jobs64, int* __restrict__ jobs128,
                           int* __restrict__ njobs)
{
    if (threadIdx.x == 0 && blockIdx.x == 0) {
        int n = 0, n2 = 0;
        for (int e = 0; e < E_NUM; ++e) {
            int mt = (cnt[e] + 63) >> 6;
            for (int m = 0; m < mt; ++m) jobs64[n++] = (e << 16) | m;
            int mt2 = (cnt[e] + 127) >> 7;
            for (int m = 0; m < mt2; ++m) jobs128[n2++] = (e << 16) | m;
        }
        njobs[0] = n;
        njobs[1] = n2;
    }
}

// ---------------- up: h = w * silu(xW1^T+b1) * (xW2^T+b2), 128x(64+64) tile ----------------
// r10-verified structure: dual-B, 84 VGPR, ~98.6 us.
__global__ __launch_bounds__(256) void up_kernel(
    const ushort* __restrict__ xbf,
    const ushort* __restrict__ w1bf, const float* __restrict__ b1,
    const ushort* __restrict__ w2bf, const float* __restrict__ b2,
    const int* __restrict__ cnt, const int* __restrict__ tok_list,
    const int* __restrict__ slot_list, const float* __restrict__ wt_slot,
    const int* __restrict__ jobs128, const int* __restrict__ njobs,
    ushort* __restrict__ h)
{
    if ((int)blockIdx.y >= njobs[1]) return;
    const int jb = jobs128[blockIdx.y];
    const int e = jb >> 16;
    const int mbase = (jb & 0xffff) * 128;
    const int M = cnt[e];
    const int nbase = blockIdx.x * 64;
    const int tid = threadIdx.x;
    const int lane = tid & 63;
    const int w = tid >> 6;

    __shared__ ushort As[128 * 64];
    __shared__ ushort B1s[64 * 64];
    __shared__ ushort B2s[64 * 64];

    const ushort* srcA[4];
    const ushort* srcB1[2];
    const ushort* srcB2[2];
    #pragma unroll
    for (int j = 0; j < 4; ++j) {
        int o = j * 4096 + tid * 16;
        int r = o >> 7;
        int cb = (o & 127) ^ ((r & 7) << 4);
        int lpos = mbase + r; if (lpos > M - 1) lpos = M - 1;
        int tok = tok_list[e * T_TOK + lpos];
        srcA[j] = xbf + (size_t)tok * H_DIM + (cb >> 1);
    }
    #pragma unroll
    for (int j = 0; j < 2; ++j) {
        int o = j * 4096 + tid * 16;
        int r = o >> 7;
        int cb = (o & 127) ^ ((r & 7) << 4);
        srcB1[j] = w1bf + ((size_t)e * DFF_D + nbase + r) * H_DIM + (cb >> 1);
        srcB2[j] = w2bf + ((size_t)e * DFF_D + nbase + r) * H_DIM + (cb >> 1);
    }

    const f32x4 zero = {0.f, 0.f, 0.f, 0.f};
    f32x4 accg[2][4], accv[2][4];
    #pragma unroll
    for (int mi = 0; mi < 2; ++mi)
        #pragma unroll
        for (int ni = 0; ni < 4; ++ni) { accg[mi][ni] = zero; accv[mi][ni] = zero; }

    const int r16 = lane & 15;
    const int g4  = lane >> 4;
    const int cb0 = g4 * 16;

    for (int k0 = 0; k0 < H_DIM; k0 += 64) {
        #pragma unroll
        for (int j = 0; j < 4; ++j)
            glds16(srcA[j] + k0, &As[j * 2048 + tid * 8]);
        #pragma unroll
        for (int j = 0; j < 2; ++j) {
            glds16(srcB1[j] + k0, &B1s[j * 2048 + tid * 8]);
            glds16(srcB2[j] + k0, &B2s[j * 2048 + tid * 8]);
        }
        __syncthreads();
        #pragma unroll
        for (int kk = 0; kk < 2; ++kk) {
            s16x8 bf1[4], bf2[4];
            #pragma unroll
            for (int ni = 0; ni < 4; ++ni) {
                bf1[ni] = lds_frag(B1s, ni * 16 + r16, kk * 64 + cb0);
                bf2[ni] = lds_frag(B2s, ni * 16 + r16, kk * 64 + cb0);
            }
            #pragma unroll
            for (int mi = 0; mi < 2; ++mi) {
                s16x8 af = lds_frag(As, w * 32 + mi * 16 + r16, kk * 64 + cb0);
                #pragma unroll
                for (int ni = 0; ni < 4; ++ni) {
                    accg[mi][ni] = __builtin_amdgcn_mfma_f32_16x16x32_bf16(af, bf1[ni], accg[mi][ni], 0, 0, 0);
                    accv[mi][ni] = __builtin_amdgcn_mfma_f32_16x16x32_bf16(af, bf2[ni], accv[mi][ni], 0, 0, 0);
                }
            }
        }
        __syncthreads();
    }

    #pragma unroll
    for (int mi = 0; mi < 2; ++mi) {
        #pragma unroll
        for (int j = 0; j < 4; ++j) {
            int p = mbase + w * 32 + mi * 16 + g4 * 4 + j;
            if (p < M) {
                int slot = slot_list[e * T_TOK + p];
                float wgt = wt_slot[slot];
                #pragma unroll
                for (int ni = 0; ni < 4; ++ni) {
                    int col = nbase + ni * 16 + r16;
                    float g = accg[mi][ni][j] + b1[e * DFF_D + col];
                    float v = accv[mi][ni][j] + b2[e * DFF_D + col];
                    float s = g / (1.f + __expf(-g));
                    h[(size_t)slot * DFF_D + col] = f2bf(wgt * s * v);
                }
            }
        }
    }
}

// ---------------- down: eo[slot] = h @ W3^T (bf16, no atomics) ----------------
// 4-phase counted-vmcnt pipeline: BM=128, BN=256, BK=64, 512 thr (8 waves 2Mx4N,
// wave 64x64), 96KB dbuf LDS (1 block/CU). Staging targets the buffer NOT read
// this iteration; vmcnt never drains to 0 in the steady loop.
__global__ __launch_bounds__(512) void down_kernel(
    const ushort* __restrict__ h,
    const ushort* __restrict__ w3bf,
    const int* __restrict__ cnt, const int* __restrict__ slot_list,
    const int* __restrict__ jobs128, const int* __restrict__ njobs,
    ushort* __restrict__ eo)
{
    if ((int)blockIdx.y >= njobs[1]) return;
    const int jb = jobs128[blockIdx.y];
    const int e = jb >> 16;
    const int mbase = (jb & 0xffff) * 128;
    const int M = cnt[e];
    const int nbase = blockIdx.x * 256;
    const int tid = threadIdx.x;
    const int lane = tid & 63;
    const int w = tid >> 6;       // 8 waves
    const int wr = w >> 2;        // 0..1: 64-row block
    const int wc = w & 3;         // 0..3: 64-col block

    __shared__ ushort As[2][128 * 64];   // 2 x 16 KB
    __shared__ ushort Bs[2][256 * 64];   // 2 x 32 KB

    // staging sources (pre-swizzled global column). A-half hA = rows [hA*64,+64),
    // 1 load/thread. B-half hB = rows [hB*128,+128), 2 loads/thread.
    const ushort* srcA[2];
    #pragma unroll
    for (int hA = 0; hA < 2; ++hA) {
        int o = tid * 16;
        int r = (o >> 7) + hA * 64;
        int cb = (o & 127) ^ ((r & 7) << 4);
        int lpos = mbase + r; if (lpos > M - 1) lpos = M - 1;
        int slot = slot_list[e * T_TOK + lpos];
        srcA[hA] = h + (size_t)slot * DFF_D + (cb >> 1);
    }
    const ushort* srcB[2][2];
    #pragma unroll
    for (int hB = 0; hB < 2; ++hB)
        #pragma unroll
        for (int j = 0; j < 2; ++j) {
            int o = j * 8192 + tid * 16;
            int r = (o >> 7) + hB * 128;
            int cb = (o & 127) ^ ((r & 7) << 4);
            srcB[hB][j] = w3bf + ((size_t)e * H_DIM + nbase + r) * DFF_D + (cb >> 1);
        }

#define DN_STAGE_A(buf, hA, koff) \
    glds16(srcA[hA] + (koff), &As[buf][(hA) * 4096 + tid * 8])
#define DN_STAGE_B(buf, hB, koff) \
    { glds16(srcB[hB][0] + (koff), &Bs[buf][(hB) * 8192 + tid * 8]); \
      glds16(srcB[hB][1] + (koff), &Bs[buf][(hB) * 8192 + 4096 + tid * 8]); }

    const f32x4 zero = {0.f, 0.f, 0.f, 0.f};
    f32x4 acc[4][4];
    #pragma unroll
    for (int mi = 0; mi < 4; ++mi)
        #pragma unroll
        for (int ni = 0; ni < 4; ++ni) acc[mi][ni] = zero;

    const int r16 = lane & 15;
    const int g4  = lane >> 4;
    const int cb0 = g4 * 16;
    const int arow = wr * 64;
    const int brow = wc * 64;

    const int NT = DFF_D / 64;   // 32

    // prologue: stage tile 0 (A0,B0 first, then A1,B1); wait only for A0,B0.
    asm volatile("s_waitcnt vmcnt(0)" ::: "memory");
    DN_STAGE_A(0, 0, 0); DN_STAGE_B(0, 0, 0);
    DN_STAGE_A(0, 1, 0); DN_STAGE_B(0, 1, 0);
    asm volatile("s_waitcnt vmcnt(3)" ::: "memory");   // A0,B0 landed; A1,B1 in flight
    PHASE_BARRIER();

    int cur = 0;
    for (int t = 0; t < NT; ++t) {
        const int koff = (t + 1) * 64;
        const bool pf = (t + 1 < NT);
        s16x8 alo[2][2], ahi[2][2], blo[2][2], bhi[2][2];

        // ---- P1: quad M0N0 (reads A0, B0 of cur; stages next A0,B0) ----
        #pragma unroll
        for (int mi = 0; mi < 2; ++mi)
            #pragma unroll
            for (int kk = 0; kk < 2; ++kk)
                alo[mi][kk] = lds_frag(As[cur], arow + mi * 16 + r16, kk * 64 + cb0);
        #pragma unroll
        for (int ni = 0; ni < 2; ++ni)
            #pragma unroll
            for (int kk = 0; kk < 2; ++kk)
                blo[ni][kk] = lds_frag(Bs[cur], brow + ni * 16 + r16, kk * 64 + cb0);
        if (pf) { DN_STAGE_A(cur ^ 1, 0, koff); DN_STAGE_B(cur ^ 1, 0, koff); }
        #pragma unroll
        for (int mi = 0; mi < 2; ++mi)
            #pragma unroll
            for (int ni = 0; ni < 2; ++ni)
                #pragma unroll
                for (int kk = 0; kk < 2; ++kk)
                    acc[mi][ni] = __builtin_amdgcn_mfma_f32_16x16x32_bf16(alo[mi][kk], blo[ni][kk], acc[mi][ni], 0, 0, 0);
        PHASE_BARRIER();

        // ---- P2: quad M0N1 (waits cur A1/B1; reads B1; stages next A1) ----
        if (pf) { asm volatile("s_waitcnt vmcnt(3)" ::: "memory"); }
        else    { asm volatile("s_waitcnt vmcnt(0)" ::: "memory"); }
        __builtin_amdgcn_sched_barrier(0);
        #pragma unroll
        for (int ni = 0; ni < 2; ++ni)
            #pragma unroll
            for (int kk = 0; kk < 2; ++kk)
                bhi[ni][kk] = lds_frag(Bs[cur], brow + (ni + 2) * 16 + r16, kk * 64 + cb0);
        if (pf) DN_STAGE_A(cur ^ 1, 1, koff);
        #pragma unroll
        for (int mi = 0; mi < 2; ++mi)
            #pragma unroll
            for (int ni = 0; ni < 2; ++ni)
                #pragma unroll
                for (int kk = 0; kk < 2; ++kk)
                    acc[mi][ni + 2] = __builtin_amdgcn_mfma_f32_16x16x32_bf16(alo[mi][kk], bhi[ni][kk], acc[mi][ni + 2], 0, 0, 0);
        PHASE_BARRIER();

        // ---- P3: quad M1N1 (reads A1; stages next B1) ----
        #pragma unroll
        for (int mi = 0; mi < 2; ++mi)
            #pragma unroll
            for (int kk = 0; kk < 2; ++kk)
                ahi[mi][kk] = lds_frag(As[cur], arow + (mi + 2) * 16 + r16, kk * 64 + cb0);
        if (pf) DN_STAGE_B(cur ^ 1, 1, koff);
        #pragma unroll
        for (int mi = 0; mi < 2; ++mi)
            #pragma unroll
            for (int ni = 0; ni < 2; ++ni)
                #pragma unroll
                for (int kk = 0; kk < 2; ++kk)
                    acc[mi + 2][ni + 2] = __builtin_amdgcn_mfma_f32_16x16x32_bf16(ahi[mi][kk], bhi[ni][kk], acc[mi + 2][ni + 2], 0, 0, 0);
        PHASE_BARRIER();

        // ---- P4: quad M1N0 (re-reads B0; end-wait for next A0,B0) ----
        #pragma unroll
        for (int ni = 0; ni < 2; ++ni)
            #pragma unroll
            for (int kk = 0; kk < 2; ++kk)
                blo[ni][kk] = lds_frag(Bs[cur], brow + ni * 16 + r16, kk * 64 + cb0);
        #pragma unroll
        for (int mi = 0; mi < 2; ++mi)
            #pragma unroll
            for (int ni = 0; ni < 2; ++ni)
                #pragma unroll
                for (int kk = 0; kk < 2; ++kk)
                    acc[mi + 2][ni] = __builtin_amdgcn_mfma_f32_16x16x32_bf16(ahi[mi][kk], blo[ni][kk], acc[mi + 2][ni], 0, 0, 0);
        if (pf) { asm volatile("s_waitcnt vmcnt(3)" ::: "memory"); }
        PHASE_BARRIER();

        cur ^= 1;
    }
#undef DN_STAGE_A
#undef DN_STAGE_B

    #pragma unroll
    for (int mi = 0; mi < 4; ++mi) {
        #pragma unroll
        for (int j = 0; j < 4; ++j) {
            int p = mbase + arow + mi * 16 + g4 * 4 + j;
            if (p < M) {
                int slot = slot_list[e * T_TOK + p];
                #pragma unroll
                for (int ni = 0; ni < 4; ++ni) {
                    int col = nbase + brow + ni * 16 + r16;
                    eo[(size_t)slot * H_DIM + col] = f2bf(acc[mi][ni][j]);
                }
            }
        }
    }
}

// ---------------- combine: out[t] = eo[2t] + eo[2t+1] + w0*b3[e0] + w1*b3[e1] ----------------
__global__ __launch_bounds__(256) void combine_kernel(
    const ushort* __restrict__ eo, const int* __restrict__ topi_packed,
    const float* __restrict__ wt_slot, const float* __restrict__ b3,
    float* __restrict__ out)
{
    const int i = blockIdx.x * 256 + threadIdx.x;     // over T*H/8
    const int t = i >> 7;
    const int c0 = (i & 127) * 8;
    const int pk = topi_packed[t];
    const int e0 = pk & 0xff, e1 = (pk >> 8) & 0xff;
    const float w0 = wt_slot[2 * t], w1 = wt_slot[2 * t + 1];
    s16x8 a = *(const s16x8*)(eo + (size_t)(2 * t) * H_DIM + c0);
    s16x8 b = *(const s16x8*)(eo + (size_t)(2 * t + 1) * H_DIM + c0);
    const float4* p0 = (const float4*)(b3 + e0 * H_DIM + c0);
    const float4* p1 = (const float4*)(b3 + e1 * H_DIM + c0);
    float4 b0a = p0[0], b0b = p0[1];
    float4 b1a = p1[0], b1b = p1[1];
    float4 r0, r1;
    r0.x = bf2f(a[0]) + bf2f(b[0]) + w0 * b0a.x + w1 * b1a.x;
    r0.y = bf2f(a[1]) + bf2f(b[1]) + w0 * b0a.y + w1 * b1a.y;
    r0.z = bf2f(a[2]) + bf2f(b[2]) + w0 * b0a.z + w1 * b1a.z;
    r0.w = bf2f(a[3]) + bf2f(b[3]) + w0 * b0a.w + w1 * b1a.w;
    r1.x = bf2f(a[4]) + bf2f(b[4]) + w0 * b0b.x + w1 * b1b.x;
    r1.y = bf2f(a[5]) + bf2f(b[5]) + w0 * b0b.y + w1 * b1b.y;
    r1.z = bf2f(a[6]) + bf2f(b[6]) + w0 * b0b.z + w1 * b1b.z;
    r1.w = bf2f(a[7]) + bf2f(b[7]) + w0 * b0b.w + w1 * b1b.w;
    float4* op = (float4*)(out + (size_t)t * H_DIM + c0);
    op[0] = r0;
    op[1] = r1;
}

extern "C" void kernel_launch(void* const* d_in, const int* in_sizes, int n_in,
                              void* d_out, int out_size, void* d_ws, size_t ws_size,
                              hipStream_t stream) {
    const float* x  = (const float*)d_in[0];
    const float* Wg = (const float*)d_in[1];
    const float* W1 = (const float*)d_in[2];
    const float* b1 = (const float*)d_in[3];
    const float* W2 = (const float*)d_in[4];
    const float* b2 = (const float*)d_in[5];
    const float* W3 = (const float*)d_in[6];
    const float* b3 = (const float*)d_in[7];
    float* out = (float*)d_out;

    char* ws = (char*)d_ws;
    int*   cnt       = (int*)(ws);
    int*   njobs     = (int*)(ws + 64);
    int*   jobs64    = (int*)(ws + 128);
    int*   jobs128   = (int*)(ws + 704);
    int*   tok_list  = (int*)(ws + 1024);
    int*   slot_list = (int*)(ws + 1024 + E_NUM * T_TOK * 4);
    float* wt_slot   = (float*)(ws + 1024 + 2 * E_NUM * T_TOK * 4);
    int*   topi      = (int*)(ws + 320 * 1024);
    ushort* xbf  = (ushort*)(ws + (size_t)1  * (1u << 20));   // 8 MB  (1..9)
    ushort* w1bf = (ushort*)(ws + (size_t)16 * (1u << 20));   // 32 MB (16..48)
    ushort* w2bf = (ushort*)(ws + (size_t)48 * (1u << 20));   // 32 MB (48..80)
    ushort* hbuf = (ushort*)(ws + (size_t)80 * (1u << 20));   // 32 MB (80..112)
    ushort* eobf = w1bf;   // reuse after up (16.8 MB)

    const bool bigws = ws_size >= ((size_t)145 << 20);
    ushort* w3bf = bigws ? (ushort*)(ws + (size_t)112 * (1u << 20)) : w2bf;

    if (bigws)
        cvtW_kernel<<<2048, 256, 0, stream>>>(W1, w1bf, W2, w2bf, W3, w3bf);
    else
        cvtW_kernel<<<2048, 256, 0, stream>>>(W1, w1bf, W2, w2bf, nullptr, nullptr);

    gate_kernel<<<T_TOK / 4, 256, 0, stream>>>(x, Wg, topi, wt_slot, xbf);
    build_lists<<<E_NUM, 256, 0, stream>>>(topi, cnt, tok_list, slot_list);
    build_jobs<<<1, 64, 0, stream>>>(cnt, jobs64, jobs128, njobs);

    dim3 gup(DFF_D / 64, MAXJOBS128);
    up_kernel<<<gup, 256, 0, stream>>>(xbf, w1bf, b1, w2bf, b2, cnt, tok_list,
                                       slot_list, wt_slot, jobs128, njobs, hbuf);

    if (!bigws)
        cvt_kernel<<<2048, 256, 0, stream>>>(W3, w3bf, E_NUM * H_DIM * DFF_D / 8);

    dim3 gdn(H_DIM / 256, MAXJOBS128);
    down_kernel<<<gdn, 512, 0, stream>>>(hbuf, w3bf, cnt, slot_list,
                                         jobs128, njobs, eobf);

    combine_kernel<<<T_TOK * H_DIM / 8 / 256, 256, 0, stream>>>(eobf, topi, wt_slot, b3, out);
}

// Round 14
// 257.217 us; speedup vs baseline: 1.1703x; 1.1703x over previous
//
#include <hip/hip_runtime.h>
#include <hip/hip_bf16.h>

#define T_TOK 4096
#define H_DIM 1024
#define DFF_D 2048
#define E_NUM 8
#define K_TOP 2
#define MAXJOBS64 136
#define MAXJOBS128 72
#define CVT_BLOCKS 2048
#define EO_OFF ((size_t)T_TOK * K_TOP * H_DIM)   // elements per split-K plane

typedef __attribute__((ext_vector_type(8))) short s16x8;
typedef __attribute__((ext_vector_type(4))) float f32x4;

__device__ __forceinline__ ushort f2bf(float f) {
    unsigned u = __float_as_uint(f);
    u = (u + 0x7FFFu + ((u >> 16) & 1u)) >> 16;  // RNE
    return (ushort)u;
}

__device__ __forceinline__ float bf2f(short s) {
    return __uint_as_float(((unsigned)(ushort)s) << 16);
}

__device__ __forceinline__ void glds16(const ushort* g, ushort* l) {
    __builtin_amdgcn_global_load_lds(
        (const __attribute__((address_space(1))) unsigned*)g,
        (__attribute__((address_space(3))) unsigned*)l, 16, 0, 0);
}

// swizzled LDS fragment read: tile stored [rows][64] bf16 (128B rows),
// source staged with matching inverse swizzle on the global address.
__device__ __forceinline__ s16x8 lds_frag(const ushort* base, int row, int bytecol) {
    int byte = row * 128 + (bytecol ^ ((row & 7) << 4));
    return *(const s16x8*)((const char*)base + byte);
}

__device__ __forceinline__ void cvt8(const float* p, ushort* dst, size_t i) {
    float4 a = ((const float4*)(p + i * 8))[0];
    float4 b = ((const float4*)(p + i * 8))[1];
    union { ushort us[8]; uint4 q; } o;
    o.us[0] = f2bf(a.x); o.us[1] = f2bf(a.y); o.us[2] = f2bf(a.z); o.us[3] = f2bf(a.w);
    o.us[4] = f2bf(b.x); o.us[5] = f2bf(b.y); o.us[6] = f2bf(b.z); o.us[7] = f2bf(b.w);
    ((uint4*)dst)[i] = o.q;
}

// ---------------- fp32 -> bf16 bulk convert ----------------
__global__ __launch_bounds__(256) void cvt_kernel(
    const float* __restrict__ in, ushort* __restrict__ out, int n8)
{
    int i = blockIdx.x * blockDim.x + threadIdx.x;
    const int stride = gridDim.x * blockDim.x;
    for (; i < n8; i += stride) cvt8(in, out, i);
}

// ---------------- fused: weight converts (blocks < CVT_BLOCKS) + gate ----------------
// Gate blocks run concurrently with the BW-bound convert -> gate time hides.
__global__ __launch_bounds__(256) void cvtW_gate_kernel(
    const float* __restrict__ W1, ushort* __restrict__ w1bf,
    const float* __restrict__ W2, ushort* __restrict__ w2bf,
    const float* __restrict__ W3, ushort* __restrict__ w3bf,   // W3 may be null
    const float* __restrict__ x,  const float* __restrict__ Wg,
    int* __restrict__ topi_packed, float* __restrict__ wt_slot,
    ushort* __restrict__ xbf)
{
    if ((int)blockIdx.x < CVT_BLOCKS) {
        const int nW = E_NUM * DFF_D * H_DIM / 8;   // 2,097,152 chunks each
        const int total = (W3 != nullptr) ? 3 * nW : 2 * nW;
        int i = blockIdx.x * 256 + threadIdx.x;
        const int stride = CVT_BLOCKS * 256;
        for (; i < total; i += stride) {
            if (i < nW)            cvt8(W1, w1bf, i);
            else if (i < 2 * nW)   cvt8(W2, w2bf, i - nW);
            else                   cvt8(W3, w3bf, i - 2 * nW);
        }
        return;
    }
    // ---- gate path: 4 tokens per block ----
    const int t = (blockIdx.x - CVT_BLOCKS) * 4 + (threadIdx.x >> 6);
    const int lane = threadIdx.x & 63;
    const float* xr = x + (size_t)t * H_DIM;
    float xv[16];
    #pragma unroll
    for (int j = 0; j < 16; ++j) xv[j] = xr[j * 64 + lane];

    ushort* xo = xbf + (size_t)t * H_DIM;
    #pragma unroll
    for (int j = 0; j < 16; ++j) xo[j * 64 + lane] = f2bf(xv[j]);

    float score[E_NUM];
    #pragma unroll
    for (int e = 0; e < E_NUM; ++e) {
        const float* wr = Wg + e * H_DIM;
        float p = 0.f;
        #pragma unroll
        for (int j = 0; j < 16; ++j) p += xv[j] * wr[j * 64 + lane];
        #pragma unroll
        for (int s = 32; s >= 1; s >>= 1) p += __shfl_xor(p, s, 64);
        score[e] = p;
    }
    if (lane == 0) {
        int i0 = 0;
        #pragma unroll
        for (int e = 1; e < E_NUM; ++e) if (score[e] > score[i0]) i0 = e;
        int i1 = (i0 == 0) ? 1 : 0;
        #pragma unroll
        for (int e = 0; e < E_NUM; ++e)
            if (e != i0 && score[e] > score[i1]) i1 = e;
        float e1 = expf(score[i1] - score[i0]);
        float w0 = 1.f / (1.f + e1);
        float w1 = e1 / (1.f + e1);
        topi_packed[t] = i0 | (i1 << 8);
        wt_slot[t * K_TOP + 0] = w0;
        wt_slot[t * K_TOP + 1] = w1;
    }
}

// ---------------- per-expert token lists via LDS atomics ----------------
__global__ __launch_bounds__(256) void build_lists(
    const int* __restrict__ topi_packed,
    int* __restrict__ cnt, int* __restrict__ tok_list, int* __restrict__ slot_list)
{
    const int e = blockIdx.x;
    __shared__ int lcnt;
    if (threadIdx.x == 0) lcnt = 0;
    __syncthreads();
    for (int t = threadIdx.x; t < T_TOK; t += 256) {
        int pk = topi_packed[t];
        int i0 = pk & 0xff;
        int i1 = (pk >> 8) & 0xff;
        if (i0 == e) {
            int p = atomicAdd(&lcnt, 1);
            tok_list[e * T_TOK + p] = t;
            slot_list[e * T_TOK + p] = t * K_TOP + 0;
        }
        if (i1 == e) {
            int p = atomicAdd(&lcnt, 1);
            tok_list[e * T_TOK + p] = t;
            slot_list[e * T_TOK + p] = t * K_TOP + 1;
        }
    }
    __syncthreads();
    if (threadIdx.x == 0) cnt[e] = lcnt;
}

// ---------------- dense (e, mtile) job lists ----------------
__global__ void build_jobs(const int* __restrict__ cnt,
                           int* __restrict__ jobs64, int* __restrict__ jobs128,
                           int* __restrict__ njobs)
{
    if (threadIdx.x == 0 && blockIdx.x == 0) {
        int n = 0, n2 = 0;
        for (int e = 0; e < E_NUM; ++e) {
            int mt = (cnt[e] + 63) >> 6;
            for (int m = 0; m < mt; ++m) jobs64[n++] = (e << 16) | m;
            int mt2 = (cnt[e] + 127) >> 7;
            for (int m = 0; m < mt2; ++m) jobs128[n2++] = (e << 16) | m;
        }
        njobs[0] = n;
        njobs[1] = n2;
    }
}

// ---------------- up: h = w * silu(xW1^T+b1) * (xW2^T+b2), 128x(64+64) tile ----------------
// r10/r12-verified structure: dual-B, 84 VGPR, ~98.6 us.
__global__ __launch_bounds__(256) void up_kernel(
    const ushort* __restrict__ xbf,
    const ushort* __restrict__ w1bf, const float* __restrict__ b1,
    const ushort* __restrict__ w2bf, const float* __restrict__ b2,
    const int* __restrict__ cnt, const int* __restrict__ tok_list,
    const int* __restrict__ slot_list, const float* __restrict__ wt_slot,
    const int* __restrict__ jobs128, const int* __restrict__ njobs,
    ushort* __restrict__ h)
{
    if ((int)blockIdx.y >= njobs[1]) return;
    const int jb = jobs128[blockIdx.y];
    const int e = jb >> 16;
    const int mbase = (jb & 0xffff) * 128;
    const int M = cnt[e];
    const int nbase = blockIdx.x * 64;
    const int tid = threadIdx.x;
    const int lane = tid & 63;
    const int w = tid >> 6;

    __shared__ ushort As[128 * 64];
    __shared__ ushort B1s[64 * 64];
    __shared__ ushort B2s[64 * 64];

    const ushort* srcA[4];
    const ushort* srcB1[2];
    const ushort* srcB2[2];
    #pragma unroll
    for (int j = 0; j < 4; ++j) {
        int o = j * 4096 + tid * 16;
        int r = o >> 7;
        int cb = (o & 127) ^ ((r & 7) << 4);
        int lpos = mbase + r; if (lpos > M - 1) lpos = M - 1;
        int tok = tok_list[e * T_TOK + lpos];
        srcA[j] = xbf + (size_t)tok * H_DIM + (cb >> 1);
    }
    #pragma unroll
    for (int j = 0; j < 2; ++j) {
        int o = j * 4096 + tid * 16;
        int r = o >> 7;
        int cb = (o & 127) ^ ((r & 7) << 4);
        srcB1[j] = w1bf + ((size_t)e * DFF_D + nbase + r) * H_DIM + (cb >> 1);
        srcB2[j] = w2bf + ((size_t)e * DFF_D + nbase + r) * H_DIM + (cb >> 1);
    }

    const f32x4 zero = {0.f, 0.f, 0.f, 0.f};
    f32x4 accg[2][4], accv[2][4];
    #pragma unroll
    for (int mi = 0; mi < 2; ++mi)
        #pragma unroll
        for (int ni = 0; ni < 4; ++ni) { accg[mi][ni] = zero; accv[mi][ni] = zero; }

    const int r16 = lane & 15;
    const int g4  = lane >> 4;
    const int cb0 = g4 * 16;

    for (int k0 = 0; k0 < H_DIM; k0 += 64) {
        #pragma unroll
        for (int j = 0; j < 4; ++j)
            glds16(srcA[j] + k0, &As[j * 2048 + tid * 8]);
        #pragma unroll
        for (int j = 0; j < 2; ++j) {
            glds16(srcB1[j] + k0, &B1s[j * 2048 + tid * 8]);
            glds16(srcB2[j] + k0, &B2s[j * 2048 + tid * 8]);
        }
        __syncthreads();
        #pragma unroll
        for (int kk = 0; kk < 2; ++kk) {
            s16x8 bf1[4], bf2[4];
            #pragma unroll
            for (int ni = 0; ni < 4; ++ni) {
                bf1[ni] = lds_frag(B1s, ni * 16 + r16, kk * 64 + cb0);
                bf2[ni] = lds_frag(B2s, ni * 16 + r16, kk * 64 + cb0);
            }
            #pragma unroll
            for (int mi = 0; mi < 2; ++mi) {
                s16x8 af = lds_frag(As, w * 32 + mi * 16 + r16, kk * 64 + cb0);
                #pragma unroll
                for (int ni = 0; ni < 4; ++ni) {
                    accg[mi][ni] = __builtin_amdgcn_mfma_f32_16x16x32_bf16(af, bf1[ni], accg[mi][ni], 0, 0, 0);
                    accv[mi][ni] = __builtin_amdgcn_mfma_f32_16x16x32_bf16(af, bf2[ni], accv[mi][ni], 0, 0, 0);
                }
            }
        }
        __syncthreads();
    }

    #pragma unroll
    for (int mi = 0; mi < 2; ++mi) {
        #pragma unroll
        for (int j = 0; j < 4; ++j) {
            int p = mbase + w * 32 + mi * 16 + g4 * 4 + j;
            if (p < M) {
                int slot = slot_list[e * T_TOK + p];
                float wgt = wt_slot[slot];
                #pragma unroll
                for (int ni = 0; ni < 4; ++ni) {
                    int col = nbase + ni * 16 + r16;
                    float g = accg[mi][ni][j] + b1[e * DFF_D + col];
                    float v = accv[mi][ni][j] + b2[e * DFF_D + col];
                    float s = g / (1.f + __expf(-g));
                    h[(size_t)slot * DFF_D + col] = f2bf(wgt * s * v);
                }
            }
        }
    }
}

// ---------------- down: eo[kc][slot] = h @ W3^T partial (bf16, no atomics) ----------------
// r12-proven core: BM=128, BN=64, 128 thr = 2 waves (wave 64x64), 24KB LDS.
// Split-K=2: kc = blockIdx.x & 1, each block does K=1024 -> 2112 blocks.
__global__ __launch_bounds__(128) void down_kernel(
    const ushort* __restrict__ h,
    const ushort* __restrict__ w3bf,
    const int* __restrict__ cnt, const int* __restrict__ slot_list,
    const int* __restrict__ jobs128, const int* __restrict__ njobs,
    ushort* __restrict__ eo)
{
    if ((int)blockIdx.y >= njobs[1]) return;
    const int jb = jobs128[blockIdx.y];
    const int e = jb >> 16;
    const int mbase = (jb & 0xffff) * 128;
    const int M = cnt[e];
    const int nbase = (blockIdx.x >> 1) * 64;
    const int kc = blockIdx.x & 1;
    const int kbeg = kc * (DFF_D / 2);
    const int tid = threadIdx.x;
    const int lane = tid & 63;
    const int w = tid >> 6;     // 2 waves

    __shared__ ushort As[128 * 64];   // 16 KB
    __shared__ ushort Bs[64 * 64];    //  8 KB

    const ushort* srcA[8];
    #pragma unroll
    for (int j = 0; j < 8; ++j) {
        int o = j * 2048 + tid * 16;
        int r = o >> 7;
        int cb = (o & 127) ^ ((r & 7) << 4);
        int lpos = mbase + r; if (lpos > M - 1) lpos = M - 1;
        int slot = slot_list[e * T_TOK + lpos];
        srcA[j] = h + (size_t)slot * DFF_D + kbeg + (cb >> 1);
    }
    const ushort* srcB[4];
    #pragma unroll
    for (int j = 0; j < 4; ++j) {
        int o = j * 2048 + tid * 16;
        int r = o >> 7;
        int cb = (o & 127) ^ ((r & 7) << 4);
        srcB[j] = w3bf + ((size_t)e * H_DIM + nbase + r) * DFF_D + kbeg + (cb >> 1);
    }

    const f32x4 zero = {0.f, 0.f, 0.f, 0.f};
    f32x4 acc[4][4];
    #pragma unroll
    for (int mi = 0; mi < 4; ++mi)
        #pragma unroll
        for (int ni = 0; ni < 4; ++ni) acc[mi][ni] = zero;

    const int r16 = lane & 15;
    const int g4  = lane >> 4;
    const int cb0 = g4 * 16;

    for (int k0 = 0; k0 < DFF_D / 2; k0 += 64) {
        #pragma unroll
        for (int j = 0; j < 8; ++j)
            glds16(srcA[j] + k0, &As[j * 1024 + tid * 8]);
        #pragma unroll
        for (int j = 0; j < 4; ++j)
            glds16(srcB[j] + k0, &Bs[j * 1024 + tid * 8]);
        __syncthreads();
        #pragma unroll
        for (int kk = 0; kk < 2; ++kk) {
            s16x8 bf[4];
            #pragma unroll
            for (int ni = 0; ni < 4; ++ni)
                bf[ni] = lds_frag(Bs, ni * 16 + r16, kk * 64 + cb0);
            #pragma unroll
            for (int mi = 0; mi < 4; ++mi) {
                s16x8 af = lds_frag(As, w * 64 + mi * 16 + r16, kk * 64 + cb0);
                #pragma unroll
                for (int ni = 0; ni < 4; ++ni)
                    acc[mi][ni] = __builtin_amdgcn_mfma_f32_16x16x32_bf16(af, bf[ni], acc[mi][ni], 0, 0, 0);
            }
        }
        __syncthreads();
    }

    ushort* eop = eo + (size_t)kc * EO_OFF;
    #pragma unroll
    for (int mi = 0; mi < 4; ++mi) {
        #pragma unroll
        for (int j = 0; j < 4; ++j) {
            int p = mbase + w * 64 + mi * 16 + g4 * 4 + j;
            if (p < M) {
                int slot = slot_list[e * T_TOK + p];
                #pragma unroll
                for (int ni = 0; ni < 4; ++ni) {
                    int col = nbase + ni * 16 + r16;
                    eop[(size_t)slot * H_DIM + col] = f2bf(acc[mi][ni][j]);
                }
            }
        }
    }
}

// ---------------- combine: out[t] = sum_kc (eo[kc][2t] + eo[kc][2t+1]) + bias ----------------
__global__ __launch_bounds__(256) void combine_kernel(
    const ushort* __restrict__ eo, const int* __restrict__ topi_packed,
    const float* __restrict__ wt_slot, const float* __restrict__ b3,
    float* __restrict__ out)
{
    const int i = blockIdx.x * 256 + threadIdx.x;     // over T*H/8
    const int t = i >> 7;
    const int c0 = (i & 127) * 8;
    const int pk = topi_packed[t];
    const int e0 = pk & 0xff, e1 = (pk >> 8) & 0xff;
    const float w0 = wt_slot[2 * t], w1 = wt_slot[2 * t + 1];
    s16x8 a0 = *(const s16x8*)(eo + (size_t)(2 * t) * H_DIM + c0);
    s16x8 b0 = *(const s16x8*)(eo + (size_t)(2 * t + 1) * H_DIM + c0);
    s16x8 a1 = *(const s16x8*)(eo + EO_OFF + (size_t)(2 * t) * H_DIM + c0);
    s16x8 b1 = *(const s16x8*)(eo + EO_OFF + (size_t)(2 * t + 1) * H_DIM + c0);
    const float4* p0 = (const float4*)(b3 + e0 * H_DIM + c0);
    const float4* p1 = (const float4*)(b3 + e1 * H_DIM + c0);
    float4 b0a = p0[0], b0b = p0[1];
    float4 b1a = p1[0], b1b = p1[1];
    float r[8];
    #pragma unroll
    for (int j = 0; j < 8; ++j)
        r[j] = (bf2f(a0[j]) + bf2f(a1[j])) + (bf2f(b0[j]) + bf2f(b1[j]));
    float4 r0, r1;
    r0.x = r[0] + w0 * b0a.x + w1 * b1a.x;
    r0.y = r[1] + w0 * b0a.y + w1 * b1a.y;
    r0.z = r[2] + w0 * b0a.z + w1 * b1a.z;
    r0.w = r[3] + w0 * b0a.w + w1 * b1a.w;
    r1.x = r[4] + w0 * b0b.x + w1 * b1b.x;
    r1.y = r[5] + w0 * b0b.y + w1 * b1b.y;
    r1.z = r[6] + w0 * b0b.z + w1 * b1b.z;
    r1.w = r[7] + w0 * b0b.w + w1 * b1b.w;
    float4* op = (float4*)(out + (size_t)t * H_DIM + c0);
    op[0] = r0;
    op[1] = r1;
}

extern "C" void kernel_launch(void* const* d_in, const int* in_sizes, int n_in,
                              void* d_out, int out_size, void* d_ws, size_t ws_size,
                              hipStream_t stream) {
    const float* x  = (const float*)d_in[0];
    const float* Wg = (const float*)d_in[1];
    const float* W1 = (const float*)d_in[2];
    const float* b1 = (const float*)d_in[3];
    const float* W2 = (const float*)d_in[4];
    const float* b2 = (const float*)d_in[5];
    const float* W3 = (const float*)d_in[6];
    const float* b3 = (const float*)d_in[7];
    float* out = (float*)d_out;

    char* ws = (char*)d_ws;
    // control block: 0..1 MB
    int*   cnt       = (int*)(ws);
    int*   njobs     = (int*)(ws + 64);
    int*   jobs64    = (int*)(ws + 128);
    int*   jobs128   = (int*)(ws + 704);
    int*   tok_list  = (int*)(ws + 1024);
    int*   slot_list = (int*)(ws + 1024 + E_NUM * T_TOK * 4);
    float* wt_slot   = (float*)(ws + 1024 + 2 * E_NUM * T_TOK * 4);
    int*   topi      = (int*)(ws + 320 * 1024);
    // phase-1 (through up): xbf 1..9, w1bf 16..48, w2bf 48..80, hbuf 80..113.6
    ushort* xbf  = (ushort*)(ws + (size_t)1  * (1u << 20));
    ushort* w1bf = (ushort*)(ws + (size_t)16 * (1u << 20));
    ushort* w2bf = (ushort*)(ws + (size_t)48 * (1u << 20));
    ushort* hbuf = (ushort*)(ws + (size_t)80 * (1u << 20));
    // phase-2 (after up): eo 4..37.6 (two 16.8MB planes), w3bf per ws_size
    ushort* eobf = (ushort*)(ws + (size_t)4  * (1u << 20));

    // W3: preconvert above hbuf if workspace allows (h ends at 113.6 MB),
    // else convert into the dead w1bf/w2bf region after up.
    const bool bigws = ws_size >= ((size_t)147 << 20);
    ushort* w3bf = bigws ? (ushort*)(ws + (size_t)114 * (1u << 20))
                         : (ushort*)(ws + (size_t)40  * (1u << 20));

    cvtW_gate_kernel<<<CVT_BLOCKS + T_TOK / 4, 256, 0, stream>>>(
        W1, w1bf, W2, w2bf, bigws ? W3 : nullptr, w3bf,
        x, Wg, topi, wt_slot, xbf);

    build_lists<<<E_NUM, 256, 0, stream>>>(topi, cnt, tok_list, slot_list);
    build_jobs<<<1, 64, 0, stream>>>(cnt, jobs64, jobs128, njobs);

    dim3 gup(DFF_D / 64, MAXJOBS128);
    up_kernel<<<gup, 256, 0, stream>>>(xbf, w1bf, b1, w2bf, b2, cnt, tok_list,
                                       slot_list, wt_slot, jobs128, njobs, hbuf);

    if (!bigws)
        cvt_kernel<<<2048, 256, 0, stream>>>(W3, w3bf, E_NUM * H_DIM * DFF_D / 8);

    dim3 gdn((H_DIM / 64) * 2, MAXJOBS128);   // x = ntile*2 (split-K)
    down_kernel<<<gdn, 128, 0, stream>>>(hbuf, w3bf, cnt, slot_list,
                                         jobs128, njobs, eobf);

    combine_kernel<<<T_TOK * H_DIM / 8 / 256, 256, 0, stream>>>(eobf, topi, wt_slot, b3, out);
}

// Round 15
// 247.773 us; speedup vs baseline: 1.2149x; 1.0381x over previous
//
#include <hip/hip_runtime.h>
#include <hip/hip_bf16.h>

#define T_TOK 4096
#define H_DIM 1024
#define DFF_D 2048
#define E_NUM 8
#define K_TOP 2
#define MAXJOBS128 72
#define CVT_BLOCKS 2048
#define W3_ROWS 8      // extra blockIdx.y rows in up's grid for W3 convert

typedef __attribute__((ext_vector_type(8))) short s16x8;
typedef __attribute__((ext_vector_type(4))) float f32x4;

__device__ __forceinline__ ushort f2bf(float f) {
    unsigned u = __float_as_uint(f);
    u = (u + 0x7FFFu + ((u >> 16) & 1u)) >> 16;  // RNE
    return (ushort)u;
}

__device__ __forceinline__ float bf2f(short s) {
    return __uint_as_float(((unsigned)(ushort)s) << 16);
}

__device__ __forceinline__ void glds16(const ushort* g, ushort* l) {
    __builtin_amdgcn_global_load_lds(
        (const __attribute__((address_space(1))) unsigned*)g,
        (__attribute__((address_space(3))) unsigned*)l, 16, 0, 0);
}

// swizzled LDS fragment read: tile stored [rows][64] bf16 (128B rows),
// source staged with matching inverse swizzle on the global address.
__device__ __forceinline__ s16x8 lds_frag(const ushort* base, int row, int bytecol) {
    int byte = row * 128 + (bytecol ^ ((row & 7) << 4));
    return *(const s16x8*)((const char*)base + byte);
}

__device__ __forceinline__ void cvt8(const float* p, ushort* dst, size_t i) {
    float4 a = ((const float4*)(p + i * 8))[0];
    float4 b = ((const float4*)(p + i * 8))[1];
    union { ushort us[8]; uint4 q; } o;
    o.us[0] = f2bf(a.x); o.us[1] = f2bf(a.y); o.us[2] = f2bf(a.z); o.us[3] = f2bf(a.w);
    o.us[4] = f2bf(b.x); o.us[5] = f2bf(b.y); o.us[6] = f2bf(b.z); o.us[7] = f2bf(b.w);
    ((uint4*)dst)[i] = o.q;
}

// inline (e, mtile) derivation from cnt[]: block y -> expert e, row base. BM=128.
__device__ __forceinline__ bool job_from_y(const int* cnt, int y, int& e, int& mbase, int& M) {
    int n = 0; mbase = -1;
    #pragma unroll
    for (int ee = 0; ee < E_NUM; ++ee) {
        int t = (cnt[ee] + 127) >> 7;
        if (mbase < 0 && y < n + t) { e = ee; mbase = (y - n) * 128; }
        n += t;
    }
    if (mbase < 0) return false;
    M = cnt[e];
    return true;
}

// ---------------- fp32 -> bf16 bulk convert (W3 fallback path) ----------------
__global__ __launch_bounds__(256) void cvt_kernel(
    const float* __restrict__ in, ushort* __restrict__ out, int n8)
{
    int i = blockIdx.x * blockDim.x + threadIdx.x;
    const int stride = gridDim.x * blockDim.x;
    for (; i < n8; i += stride) cvt8(in, out, i);
}

// ---------------- fused: W1/W2 converts (blocks < CVT_BLOCKS) + gate ----------------
__global__ __launch_bounds__(256) void cvtW_gate_kernel(
    const float* __restrict__ W1, ushort* __restrict__ w1bf,
    const float* __restrict__ W2, ushort* __restrict__ w2bf,
    const float* __restrict__ x,  const float* __restrict__ Wg,
    int* __restrict__ topi_packed, float* __restrict__ wt_slot,
    ushort* __restrict__ xbf)
{
    if ((int)blockIdx.x < CVT_BLOCKS) {
        const int nW = E_NUM * DFF_D * H_DIM / 8;   // 2,097,152 chunks each
        int i = blockIdx.x * 256 + threadIdx.x;
        const int stride = CVT_BLOCKS * 256;
        for (; i < 2 * nW; i += stride) {
            if (i < nW) cvt8(W1, w1bf, i);
            else        cvt8(W2, w2bf, i - nW);
        }
        return;
    }
    // ---- gate path: 4 tokens per block ----
    const int t = (blockIdx.x - CVT_BLOCKS) * 4 + (threadIdx.x >> 6);
    const int lane = threadIdx.x & 63;
    const float* xr = x + (size_t)t * H_DIM;
    float xv[16];
    #pragma unroll
    for (int j = 0; j < 16; ++j) xv[j] = xr[j * 64 + lane];

    ushort* xo = xbf + (size_t)t * H_DIM;
    #pragma unroll
    for (int j = 0; j < 16; ++j) xo[j * 64 + lane] = f2bf(xv[j]);

    float score[E_NUM];
    #pragma unroll
    for (int e = 0; e < E_NUM; ++e) {
        const float* wr = Wg + e * H_DIM;
        float p = 0.f;
        #pragma unroll
        for (int j = 0; j < 16; ++j) p += xv[j] * wr[j * 64 + lane];
        #pragma unroll
        for (int s = 32; s >= 1; s >>= 1) p += __shfl_xor(p, s, 64);
        score[e] = p;
    }
    if (lane == 0) {
        int i0 = 0;
        #pragma unroll
        for (int e = 1; e < E_NUM; ++e) if (score[e] > score[i0]) i0 = e;
        int i1 = (i0 == 0) ? 1 : 0;
        #pragma unroll
        for (int e = 0; e < E_NUM; ++e)
            if (e != i0 && score[e] > score[i1]) i1 = e;
        float e1 = expf(score[i1] - score[i0]);
        float w0 = 1.f / (1.f + e1);
        float w1 = e1 / (1.f + e1);
        topi_packed[t] = i0 | (i1 << 8);
        wt_slot[t * K_TOP + 0] = w0;
        wt_slot[t * K_TOP + 1] = w1;
    }
}

// ---------------- per-expert token lists via LDS atomics ----------------
__global__ __launch_bounds__(256) void build_lists(
    const int* __restrict__ topi_packed,
    int* __restrict__ cnt, int* __restrict__ tok_list, int* __restrict__ slot_list)
{
    const int e = blockIdx.x;
    __shared__ int lcnt;
    if (threadIdx.x == 0) lcnt = 0;
    __syncthreads();
    for (int t = threadIdx.x; t < T_TOK; t += 256) {
        int pk = topi_packed[t];
        int i0 = pk & 0xff;
        int i1 = (pk >> 8) & 0xff;
        if (i0 == e) {
            int p = atomicAdd(&lcnt, 1);
            tok_list[e * T_TOK + p] = t;
            slot_list[e * T_TOK + p] = t * K_TOP + 0;
        }
        if (i1 == e) {
            int p = atomicAdd(&lcnt, 1);
            tok_list[e * T_TOK + p] = t;
            slot_list[e * T_TOK + p] = t * K_TOP + 1;
        }
    }
    __syncthreads();
    if (threadIdx.x == 0) cnt[e] = lcnt;
}

// ---------------- up: h = w * silu(xW1^T+b1) * (xW2^T+b2), 128x(64+64) tile ----------------
// r10/r12-verified GEMM core (dual-B, 84 VGPR). Extra y-rows (y >= MAXJOBS128)
// grid-stride convert W3 -> bf16 concurrently (up is latency-bound, has BW headroom).
__global__ __launch_bounds__(256) void up_kernel(
    const ushort* __restrict__ xbf,
    const ushort* __restrict__ w1bf, const float* __restrict__ b1,
    const ushort* __restrict__ w2bf, const float* __restrict__ b2,
    const int* __restrict__ cnt, const int* __restrict__ tok_list,
    const int* __restrict__ slot_list, const float* __restrict__ wt_slot,
    const float* __restrict__ W3src, ushort* __restrict__ w3dst,
    ushort* __restrict__ h)
{
    if ((int)blockIdx.y >= MAXJOBS128) {
        if (W3src != nullptr) {
            const int nW3 = E_NUM * H_DIM * DFF_D / 8;   // 2,097,152 chunks
            int i = ((blockIdx.y - MAXJOBS128) * gridDim.x + blockIdx.x) * 256 + threadIdx.x;
            const int stride = W3_ROWS * gridDim.x * 256;
            for (; i < nW3; i += stride) cvt8(W3src, w3dst, i);
        }
        return;
    }
    int e, mbase, M;
    if (!job_from_y(cnt, blockIdx.y, e, mbase, M)) return;
    const int nbase = blockIdx.x * 64;
    const int tid = threadIdx.x;
    const int lane = tid & 63;
    const int w = tid >> 6;

    __shared__ ushort As[128 * 64];
    __shared__ ushort B1s[64 * 64];
    __shared__ ushort B2s[64 * 64];

    const ushort* srcA[4];
    const ushort* srcB1[2];
    const ushort* srcB2[2];
    #pragma unroll
    for (int j = 0; j < 4; ++j) {
        int o = j * 4096 + tid * 16;
        int r = o >> 7;
        int cb = (o & 127) ^ ((r & 7) << 4);
        int lpos = mbase + r; if (lpos > M - 1) lpos = M - 1;
        int tok = tok_list[e * T_TOK + lpos];
        srcA[j] = xbf + (size_t)tok * H_DIM + (cb >> 1);
    }
    #pragma unroll
    for (int j = 0; j < 2; ++j) {
        int o = j * 4096 + tid * 16;
        int r = o >> 7;
        int cb = (o & 127) ^ ((r & 7) << 4);
        srcB1[j] = w1bf + ((size_t)e * DFF_D + nbase + r) * H_DIM + (cb >> 1);
        srcB2[j] = w2bf + ((size_t)e * DFF_D + nbase + r) * H_DIM + (cb >> 1);
    }

    const f32x4 zero = {0.f, 0.f, 0.f, 0.f};
    f32x4 accg[2][4], accv[2][4];
    #pragma unroll
    for (int mi = 0; mi < 2; ++mi)
        #pragma unroll
        for (int ni = 0; ni < 4; ++ni) { accg[mi][ni] = zero; accv[mi][ni] = zero; }

    const int r16 = lane & 15;
    const int g4  = lane >> 4;
    const int cb0 = g4 * 16;

    for (int k0 = 0; k0 < H_DIM; k0 += 64) {
        #pragma unroll
        for (int j = 0; j < 4; ++j)
            glds16(srcA[j] + k0, &As[j * 2048 + tid * 8]);
        #pragma unroll
        for (int j = 0; j < 2; ++j) {
            glds16(srcB1[j] + k0, &B1s[j * 2048 + tid * 8]);
            glds16(srcB2[j] + k0, &B2s[j * 2048 + tid * 8]);
        }
        __syncthreads();
        #pragma unroll
        for (int kk = 0; kk < 2; ++kk) {
            s16x8 bf1[4], bf2[4];
            #pragma unroll
            for (int ni = 0; ni < 4; ++ni) {
                bf1[ni] = lds_frag(B1s, ni * 16 + r16, kk * 64 + cb0);
                bf2[ni] = lds_frag(B2s, ni * 16 + r16, kk * 64 + cb0);
            }
            #pragma unroll
            for (int mi = 0; mi < 2; ++mi) {
                s16x8 af = lds_frag(As, w * 32 + mi * 16 + r16, kk * 64 + cb0);
                #pragma unroll
                for (int ni = 0; ni < 4; ++ni) {
                    accg[mi][ni] = __builtin_amdgcn_mfma_f32_16x16x32_bf16(af, bf1[ni], accg[mi][ni], 0, 0, 0);
                    accv[mi][ni] = __builtin_amdgcn_mfma_f32_16x16x32_bf16(af, bf2[ni], accv[mi][ni], 0, 0, 0);
                }
            }
        }
        __syncthreads();
    }

    #pragma unroll
    for (int mi = 0; mi < 2; ++mi) {
        #pragma unroll
        for (int j = 0; j < 4; ++j) {
            int p = mbase + w * 32 + mi * 16 + g4 * 4 + j;
            if (p < M) {
                int slot = slot_list[e * T_TOK + p];
                float wgt = wt_slot[slot];
                #pragma unroll
                for (int ni = 0; ni < 4; ++ni) {
                    int col = nbase + ni * 16 + r16;
                    float g = accg[mi][ni][j] + b1[e * DFF_D + col];
                    float v = accv[mi][ni][j] + b2[e * DFF_D + col];
                    float s = g / (1.f + __expf(-g));
                    h[(size_t)slot * DFF_D + col] = f2bf(wgt * s * v);
                }
            }
        }
    }
}

// ---------------- down: eo[kc][slot] = h @ W3^T partial (bf16, no atomics) ----------------
// r12-proven core: BM=128, BN=64, 128 thr = 2 waves (wave 64x64), 24KB LDS.
// Split-K=2: kc = blockIdx.x & 1.
__global__ __launch_bounds__(128) void down_kernel(
    const ushort* __restrict__ h,
    const ushort* __restrict__ w3bf,
    const int* __restrict__ cnt, const int* __restrict__ slot_list,
    ushort* __restrict__ eo0, ushort* __restrict__ eo1)
{
    int e, mbase, M;
    if (!job_from_y(cnt, blockIdx.y, e, mbase, M)) return;
    const int nbase = (blockIdx.x >> 1) * 64;
    const int kc = blockIdx.x & 1;
    const int kbeg = kc * (DFF_D / 2);
    const int tid = threadIdx.x;
    const int lane = tid & 63;
    const int w = tid >> 6;     // 2 waves

    __shared__ ushort As[128 * 64];   // 16 KB
    __shared__ ushort Bs[64 * 64];    //  8 KB

    const ushort* srcA[8];
    #pragma unroll
    for (int j = 0; j < 8; ++j) {
        int o = j * 2048 + tid * 16;
        int r = o >> 7;
        int cb = (o & 127) ^ ((r & 7) << 4);
        int lpos = mbase + r; if (lpos > M - 1) lpos = M - 1;
        int slot = slot_list[e * T_TOK + lpos];
        srcA[j] = h + (size_t)slot * DFF_D + kbeg + (cb >> 1);
    }
    const ushort* srcB[4];
    #pragma unroll
    for (int j = 0; j < 4; ++j) {
        int o = j * 2048 + tid * 16;
        int r = o >> 7;
        int cb = (o & 127) ^ ((r & 7) << 4);
        srcB[j] = w3bf + ((size_t)e * H_DIM + nbase + r) * DFF_D + kbeg + (cb >> 1);
    }

    const f32x4 zero = {0.f, 0.f, 0.f, 0.f};
    f32x4 acc[4][4];
    #pragma unroll
    for (int mi = 0; mi < 4; ++mi)
        #pragma unroll
        for (int ni = 0; ni < 4; ++ni) acc[mi][ni] = zero;

    const int r16 = lane & 15;
    const int g4  = lane >> 4;
    const int cb0 = g4 * 16;

    for (int k0 = 0; k0 < DFF_D / 2; k0 += 64) {
        #pragma unroll
        for (int j = 0; j < 8; ++j)
            glds16(srcA[j] + k0, &As[j * 1024 + tid * 8]);
        #pragma unroll
        for (int j = 0; j < 4; ++j)
            glds16(srcB[j] + k0, &Bs[j * 1024 + tid * 8]);
        __syncthreads();
        #pragma unroll
        for (int kk = 0; kk < 2; ++kk) {
            s16x8 bf[4];
            #pragma unroll
            for (int ni = 0; ni < 4; ++ni)
                bf[ni] = lds_frag(Bs, ni * 16 + r16, kk * 64 + cb0);
            #pragma unroll
            for (int mi = 0; mi < 4; ++mi) {
                s16x8 af = lds_frag(As, w * 64 + mi * 16 + r16, kk * 64 + cb0);
                #pragma unroll
                for (int ni = 0; ni < 4; ++ni)
                    acc[mi][ni] = __builtin_amdgcn_mfma_f32_16x16x32_bf16(af, bf[ni], acc[mi][ni], 0, 0, 0);
            }
        }
        __syncthreads();
    }

    ushort* eop = kc ? eo1 : eo0;
    #pragma unroll
    for (int mi = 0; mi < 4; ++mi) {
        #pragma unroll
        for (int j = 0; j < 4; ++j) {
            int p = mbase + w * 64 + mi * 16 + g4 * 4 + j;
            if (p < M) {
                int slot = slot_list[e * T_TOK + p];
                #pragma unroll
                for (int ni = 0; ni < 4; ++ni) {
                    int col = nbase + ni * 16 + r16;
                    eop[(size_t)slot * H_DIM + col] = f2bf(acc[mi][ni][j]);
                }
            }
        }
    }
}

// ---------------- combine: out[t] = sum_kc,k (eo[kc][slot]) + w·b3 ----------------
__global__ __launch_bounds__(256) void combine_kernel(
    const ushort* __restrict__ eo0, const ushort* __restrict__ eo1,
    const int* __restrict__ topi_packed,
    const float* __restrict__ wt_slot, const float* __restrict__ b3,
    float* __restrict__ out)
{
    const int i = blockIdx.x * 256 + threadIdx.x;     // over T*H/8
    const int t = i >> 7;
    const int c0 = (i & 127) * 8;
    const int pk = topi_packed[t];
    const int e0 = pk & 0xff, e1 = (pk >> 8) & 0xff;
    const float w0 = wt_slot[2 * t], w1 = wt_slot[2 * t + 1];
    s16x8 a0 = *(const s16x8*)(eo0 + (size_t)(2 * t) * H_DIM + c0);
    s16x8 b0 = *(const s16x8*)(eo0 + (size_t)(2 * t + 1) * H_DIM + c0);
    s16x8 a1 = *(const s16x8*)(eo1 + (size_t)(2 * t) * H_DIM + c0);
    s16x8 b1 = *(const s16x8*)(eo1 + (size_t)(2 * t + 1) * H_DIM + c0);
    const float4* p0 = (const float4*)(b3 + e0 * H_DIM + c0);
    const float4* p1 = (const float4*)(b3 + e1 * H_DIM + c0);
    float4 b0a = p0[0], b0b = p0[1];
    float4 b1a = p1[0], b1b = p1[1];
    float r[8];
    #pragma unroll
    for (int j = 0; j < 8; ++j)
        r[j] = (bf2f(a0[j]) + bf2f(a1[j])) + (bf2f(b0[j]) + bf2f(b1[j]));
    float4 r0, r1;
    r0.x = r[0] + w0 * b0a.x + w1 * b1a.x;
    r0.y = r[1] + w0 * b0a.y + w1 * b1a.y;
    r0.z = r[2] + w0 * b0a.z + w1 * b1a.z;
    r0.w = r[3] + w0 * b0a.w + w1 * b1a.w;
    r1.x = r[4] + w0 * b0b.x + w1 * b1b.x;
    r1.y = r[5] + w0 * b0b.y + w1 * b1b.y;
    r1.z = r[6] + w0 * b0b.z + w1 * b1b.z;
    r1.w = r[7] + w0 * b0b.w + w1 * b1b.w;
    float4* op = (float4*)(out + (size_t)t * H_DIM + c0);
    op[0] = r0;
    op[1] = r1;
}

extern "C" void kernel_launch(void* const* d_in, const int* in_sizes, int n_in,
                              void* d_out, int out_size, void* d_ws, size_t ws_size,
                              hipStream_t stream) {
    const float* x  = (const float*)d_in[0];
    const float* Wg = (const float*)d_in[1];
    const float* W1 = (const float*)d_in[2];
    const float* b1 = (const float*)d_in[3];
    const float* W2 = (const float*)d_in[4];
    const float* b2 = (const float*)d_in[5];
    const float* W3 = (const float*)d_in[6];
    const float* b3 = (const float*)d_in[7];
    float* out = (float*)d_out;

    char* ws = (char*)d_ws;
    // control block: 0..1 MB
    int*   cnt       = (int*)(ws);
    int*   tok_list  = (int*)(ws + 1024);
    int*   slot_list = (int*)(ws + 1024 + E_NUM * T_TOK * 4);
    float* wt_slot   = (float*)(ws + 1024 + 2 * E_NUM * T_TOK * 4);
    int*   topi      = (int*)(ws + 320 * 1024);
    // phase-1 (through up): xbf 1..9, w1bf 16..48, w2bf 48..80, hbuf 80..113.6
    ushort* xbf  = (ushort*)(ws + (size_t)1  * (1u << 20));
    ushort* w1bf = (ushort*)(ws + (size_t)16 * (1u << 20));
    ushort* w2bf = (ushort*)(ws + (size_t)48 * (1u << 20));
    ushort* hbuf = (ushort*)(ws + (size_t)80 * (1u << 20));
    // phase-2 (after up): eo planes in dead xbf/w1 region
    ushort* eo0 = (ushort*)(ws + (size_t)4  * (1u << 20));   //  4..20.8
    ushort* eo1 = (ushort*)(ws + (size_t)21 * (1u << 20));   // 21..37.8

    // W3 bf16: dedicated region above hbuf if workspace allows (converted
    // concurrently inside up's grid), else dead w1/w2 region converted after up.
    const bool bigws = ws_size >= ((size_t)147 << 20);
    ushort* w3bf = bigws ? (ushort*)(ws + (size_t)114 * (1u << 20))   // 114..147.6
                         : (ushort*)(ws + (size_t)40  * (1u << 20));  //  40..73.6 (dead w1/w2)

    cvtW_gate_kernel<<<CVT_BLOCKS + T_TOK / 4, 256, 0, stream>>>(
        W1, w1bf, W2, w2bf, x, Wg, topi, wt_slot, xbf);

    build_lists<<<E_NUM, 256, 0, stream>>>(topi, cnt, tok_list, slot_list);

    dim3 gup(DFF_D / 64, MAXJOBS128 + W3_ROWS);
    up_kernel<<<gup, 256, 0, stream>>>(xbf, w1bf, b1, w2bf, b2, cnt, tok_list,
                                       slot_list, wt_slot,
                                       bigws ? W3 : nullptr, w3bf, hbuf);

    if (!bigws)
        cvt_kernel<<<2048, 256, 0, stream>>>(W3, w3bf, E_NUM * H_DIM * DFF_D / 8);

    dim3 gdn((H_DIM / 64) * 2, MAXJOBS128);   // x = ntile*2 (split-K)
    down_kernel<<<gdn, 128, 0, stream>>>(hbuf, w3bf, cnt, slot_list, eo0, eo1);

    combine_kernel<<<T_TOK * H_DIM / 8 / 256, 256, 0, stream>>>(eo0, eo1, topi, wt_slot, b3, out);
}

// Round 16
// 247.758 us; speedup vs baseline: 1.2149x; 1.0001x over previous
//
#include <hip/hip_runtime.h>
#include <hip/hip_bf16.h>

#define T_TOK 4096
#define H_DIM 1024
#define DFF_D 2048
#define E_NUM 8
#define K_TOP 2
#define MAXJOBS64 136
#define CVT_BLOCKS 2048
#define W3_ROWS 16     // extra blockIdx.y rows in up's grid for W3 convert

typedef __attribute__((ext_vector_type(8))) short s16x8;
typedef __attribute__((ext_vector_type(4))) float f32x4;

__device__ __forceinline__ ushort f2bf(float f) {
    unsigned u = __float_as_uint(f);
    u = (u + 0x7FFFu + ((u >> 16) & 1u)) >> 16;  // RNE
    return (ushort)u;
}

__device__ __forceinline__ float bf2f(short s) {
    return __uint_as_float(((unsigned)(ushort)s) << 16);
}

__device__ __forceinline__ void glds16(const ushort* g, ushort* l) {
    __builtin_amdgcn_global_load_lds(
        (const __attribute__((address_space(1))) unsigned*)g,
        (__attribute__((address_space(3))) unsigned*)l, 16, 0, 0);
}

// swizzled LDS fragment read: tile stored [rows][64] bf16 (128B rows),
// source staged with matching inverse swizzle on the global address.
__device__ __forceinline__ s16x8 lds_frag(const ushort* base, int row, int bytecol) {
    int byte = row * 128 + (bytecol ^ ((row & 7) << 4));
    return *(const s16x8*)((const char*)base + byte);
}

__device__ __forceinline__ void cvt8(const float* p, ushort* dst, size_t i) {
    float4 a = ((const float4*)(p + i * 8))[0];
    float4 b = ((const float4*)(p + i * 8))[1];
    union { ushort us[8]; uint4 q; } o;
    o.us[0] = f2bf(a.x); o.us[1] = f2bf(a.y); o.us[2] = f2bf(a.z); o.us[3] = f2bf(a.w);
    o.us[4] = f2bf(b.x); o.us[5] = f2bf(b.y); o.us[6] = f2bf(b.z); o.us[7] = f2bf(b.w);
    ((uint4*)dst)[i] = o.q;
}

// inline (e, mtile) derivation from cnt[], BM=64 granularity.
__device__ __forceinline__ bool job_from_y64(const int* cnt, int y, int& e, int& mbase, int& M) {
    int n = 0; mbase = -1;
    #pragma unroll
    for (int ee = 0; ee < E_NUM; ++ee) {
        int t = (cnt[ee] + 63) >> 6;
        if (mbase < 0 && y < n + t) { e = ee; mbase = (y - n) * 64; }
        n += t;
    }
    if (mbase < 0) return false;
    M = cnt[e];
    return true;
}

// inline (e, mtile) derivation from cnt[], BM=128 granularity (down).
__device__ __forceinline__ bool job_from_y128(const int* cnt, int y, int& e, int& mbase, int& M) {
    int n = 0; mbase = -1;
    #pragma unroll
    for (int ee = 0; ee < E_NUM; ++ee) {
        int t = (cnt[ee] + 127) >> 7;
        if (mbase < 0 && y < n + t) { e = ee; mbase = (y - n) * 128; }
        n += t;
    }
    if (mbase < 0) return false;
    M = cnt[e];
    return true;
}

// ---------------- fp32 -> bf16 bulk convert (W3 fallback path) ----------------
__global__ __launch_bounds__(256) void cvt_kernel(
    const float* __restrict__ in, ushort* __restrict__ out, int n8)
{
    int i = blockIdx.x * blockDim.x + threadIdx.x;
    const int stride = gridDim.x * blockDim.x;
    for (; i < n8; i += stride) cvt8(in, out, i);
}

// ---------------- fused: W1/W2 converts (blocks < CVT_BLOCKS) + gate ----------------
__global__ __launch_bounds__(256) void cvtW_gate_kernel(
    const float* __restrict__ W1, ushort* __restrict__ w1bf,
    const float* __restrict__ W2, ushort* __restrict__ w2bf,
    const float* __restrict__ x,  const float* __restrict__ Wg,
    int* __restrict__ topi_packed, float* __restrict__ wt_slot,
    ushort* __restrict__ xbf)
{
    if ((int)blockIdx.x < CVT_BLOCKS) {
        const int nW = E_NUM * DFF_D * H_DIM / 8;   // 2,097,152 chunks each
        int i = blockIdx.x * 256 + threadIdx.x;
        const int stride = CVT_BLOCKS * 256;
        for (; i < 2 * nW; i += stride) {
            if (i < nW) cvt8(W1, w1bf, i);
            else        cvt8(W2, w2bf, i - nW);
        }
        return;
    }
    // ---- gate path: 4 tokens per block ----
    const int t = (blockIdx.x - CVT_BLOCKS) * 4 + (threadIdx.x >> 6);
    const int lane = threadIdx.x & 63;
    const float* xr = x + (size_t)t * H_DIM;
    float xv[16];
    #pragma unroll
    for (int j = 0; j < 16; ++j) xv[j] = xr[j * 64 + lane];

    ushort* xo = xbf + (size_t)t * H_DIM;
    #pragma unroll
    for (int j = 0; j < 16; ++j) xo[j * 64 + lane] = f2bf(xv[j]);

    float score[E_NUM];
    #pragma unroll
    for (int e = 0; e < E_NUM; ++e) {
        const float* wr = Wg + e * H_DIM;
        float p = 0.f;
        #pragma unroll
        for (int j = 0; j < 16; ++j) p += xv[j] * wr[j * 64 + lane];
        #pragma unroll
        for (int s = 32; s >= 1; s >>= 1) p += __shfl_xor(p, s, 64);
        score[e] = p;
    }
    if (lane == 0) {
        int i0 = 0;
        #pragma unroll
        for (int e = 1; e < E_NUM; ++e) if (score[e] > score[i0]) i0 = e;
        int i1 = (i0 == 0) ? 1 : 0;
        #pragma unroll
        for (int e = 0; e < E_NUM; ++e)
            if (e != i0 && score[e] > score[i1]) i1 = e;
        float e1 = expf(score[i1] - score[i0]);
        float w0 = 1.f / (1.f + e1);
        float w1 = e1 / (1.f + e1);
        topi_packed[t] = i0 | (i1 << 8);
        wt_slot[t * K_TOP + 0] = w0;
        wt_slot[t * K_TOP + 1] = w1;
    }
}

// ---------------- per-expert token lists via LDS atomics ----------------
__global__ __launch_bounds__(256) void build_lists(
    const int* __restrict__ topi_packed,
    int* __restrict__ cnt, int* __restrict__ tok_list, int* __restrict__ slot_list)
{
    const int e = blockIdx.x;
    __shared__ int lcnt;
    if (threadIdx.x == 0) lcnt = 0;
    __syncthreads();
    for (int t = threadIdx.x; t < T_TOK; t += 256) {
        int pk = topi_packed[t];
        int i0 = pk & 0xff;
        int i1 = (pk >> 8) & 0xff;
        if (i0 == e) {
            int p = atomicAdd(&lcnt, 1);
            tok_list[e * T_TOK + p] = t;
            slot_list[e * T_TOK + p] = t * K_TOP + 0;
        }
        if (i1 == e) {
            int p = atomicAdd(&lcnt, 1);
            tok_list[e * T_TOK + p] = t;
            slot_list[e * T_TOK + p] = t * K_TOP + 1;
        }
    }
    __syncthreads();
    if (threadIdx.x == 0) cnt[e] = lcnt;
}

// ---------------- up: h = w * silu(xW1^T+b1) * (xW2^T+b2), 64x(64+64) tile ----------------
// r6-measured core (96.5 us, VGPR 48, occ 46%). Extra y-rows convert W3 concurrently.
__global__ __launch_bounds__(256) void up_kernel(
    const ushort* __restrict__ xbf,
    const ushort* __restrict__ w1bf, const float* __restrict__ b1,
    const ushort* __restrict__ w2bf, const float* __restrict__ b2,
    const int* __restrict__ cnt, const int* __restrict__ tok_list,
    const int* __restrict__ slot_list, const float* __restrict__ wt_slot,
    const float* __restrict__ W3src, ushort* __restrict__ w3dst,
    ushort* __restrict__ h)
{
    if ((int)blockIdx.y >= MAXJOBS64) {
        if (W3src != nullptr) {
            const int nW3 = E_NUM * H_DIM * DFF_D / 8;   // 2,097,152 chunks
            int i = ((blockIdx.y - MAXJOBS64) * gridDim.x + blockIdx.x) * 256 + threadIdx.x;
            const int stride = W3_ROWS * gridDim.x * 256;
            for (; i < nW3; i += stride) cvt8(W3src, w3dst, i);
        }
        return;
    }
    int e, mbase, M;
    if (!job_from_y64(cnt, blockIdx.y, e, mbase, M)) return;
    const int nbase = blockIdx.x * 64;
    const int tid = threadIdx.x;
    const int lane = tid & 63;
    const int w = tid >> 6;

    __shared__ ushort As[64 * 64];
    __shared__ ushort B1s[64 * 64];
    __shared__ ushort B2s[64 * 64];

    const ushort* srcA[2];
    const ushort* srcB1[2];
    const ushort* srcB2[2];
    #pragma unroll
    for (int j = 0; j < 2; ++j) {
        int o = j * 4096 + tid * 16;
        int r = o >> 7;
        int cb = (o & 127) ^ ((r & 7) << 4);
        int lpos = mbase + r; if (lpos > M - 1) lpos = M - 1;
        int tok = tok_list[e * T_TOK + lpos];
        srcA[j]  = xbf + (size_t)tok * H_DIM + (cb >> 1);
        srcB1[j] = w1bf + ((size_t)e * DFF_D + nbase + r) * H_DIM + (cb >> 1);
        srcB2[j] = w2bf + ((size_t)e * DFF_D + nbase + r) * H_DIM + (cb >> 1);
    }

    const f32x4 zero = {0.f, 0.f, 0.f, 0.f};
    f32x4 accg[4], accv[4];
    #pragma unroll
    for (int ni = 0; ni < 4; ++ni) { accg[ni] = zero; accv[ni] = zero; }

    const int r16 = lane & 15;
    const int g4  = lane >> 4;
    const int cb0 = g4 * 16;

    for (int k0 = 0; k0 < H_DIM; k0 += 64) {
        #pragma unroll
        for (int j = 0; j < 2; ++j) {
            glds16(srcA[j]  + k0, &As[j * 2048 + tid * 8]);
            glds16(srcB1[j] + k0, &B1s[j * 2048 + tid * 8]);
            glds16(srcB2[j] + k0, &B2s[j * 2048 + tid * 8]);
        }
        __syncthreads();
        #pragma unroll
        for (int kk = 0; kk < 2; ++kk) {
            s16x8 af = lds_frag(As, w * 16 + r16, kk * 64 + cb0);
            #pragma unroll
            for (int ni = 0; ni < 4; ++ni) {
                s16x8 bf1 = lds_frag(B1s, ni * 16 + r16, kk * 64 + cb0);
                s16x8 bf2 = lds_frag(B2s, ni * 16 + r16, kk * 64 + cb0);
                accg[ni] = __builtin_amdgcn_mfma_f32_16x16x32_bf16(af, bf1, accg[ni], 0, 0, 0);
                accv[ni] = __builtin_amdgcn_mfma_f32_16x16x32_bf16(af, bf2, accv[ni], 0, 0, 0);
            }
        }
        __syncthreads();
    }

    #pragma unroll
    for (int j = 0; j < 4; ++j) {
        int p = mbase + w * 16 + g4 * 4 + j;
        if (p < M) {
            int slot = slot_list[e * T_TOK + p];
            float wgt = wt_slot[slot];
            #pragma unroll
            for (int ni = 0; ni < 4; ++ni) {
                int col = nbase + ni * 16 + r16;
                float g = accg[ni][j] + b1[e * DFF_D + col];
                float v = accv[ni][j] + b2[e * DFF_D + col];
                float s = g / (1.f + __expf(-g));
                h[(size_t)slot * DFF_D + col] = f2bf(wgt * s * v);
            }
        }
    }
}

// ---------------- down: eo[kc][slot] = h @ W3^T partial (bf16, no atomics) ----------------
// r12-proven core: BM=128, BN=64, 128 thr = 2 waves (wave 64x64), 24KB LDS.
// Split-K=2: kc = blockIdx.x & 1.
__global__ __launch_bounds__(128) void down_kernel(
    const ushort* __restrict__ h,
    const ushort* __restrict__ w3bf,
    const int* __restrict__ cnt, const int* __restrict__ slot_list,
    ushort* __restrict__ eo0, ushort* __restrict__ eo1)
{
    int e, mbase, M;
    if (!job_from_y128(cnt, blockIdx.y, e, mbase, M)) return;
    const int nbase = (blockIdx.x >> 1) * 64;
    const int kc = blockIdx.x & 1;
    const int kbeg = kc * (DFF_D / 2);
    const int tid = threadIdx.x;
    const int lane = tid & 63;
    const int w = tid >> 6;     // 2 waves

    __shared__ ushort As[128 * 64];   // 16 KB
    __shared__ ushort Bs[64 * 64];    //  8 KB

    const ushort* srcA[8];
    #pragma unroll
    for (int j = 0; j < 8; ++j) {
        int o = j * 2048 + tid * 16;
        int r = o >> 7;
        int cb = (o & 127) ^ ((r & 7) << 4);
        int lpos = mbase + r; if (lpos > M - 1) lpos = M - 1;
        int slot = slot_list[e * T_TOK + lpos];
        srcA[j] = h + (size_t)slot * DFF_D + kbeg + (cb >> 1);
    }
    const ushort* srcB[4];
    #pragma unroll
    for (int j = 0; j < 4; ++j) {
        int o = j * 2048 + tid * 16;
        int r = o >> 7;
        int cb = (o & 127) ^ ((r & 7) << 4);
        srcB[j] = w3bf + ((size_t)e * H_DIM + nbase + r) * DFF_D + kbeg + (cb >> 1);
    }

    const f32x4 zero = {0.f, 0.f, 0.f, 0.f};
    f32x4 acc[4][4];
    #pragma unroll
    for (int mi = 0; mi < 4; ++mi)
        #pragma unroll
        for (int ni = 0; ni < 4; ++ni) acc[mi][ni] = zero;

    const int r16 = lane & 15;
    const int g4  = lane >> 4;
    const int cb0 = g4 * 16;

    for (int k0 = 0; k0 < DFF_D / 2; k0 += 64) {
        #pragma unroll
        for (int j = 0; j < 8; ++j)
            glds16(srcA[j] + k0, &As[j * 1024 + tid * 8]);
        #pragma unroll
        for (int j = 0; j < 4; ++j)
            glds16(srcB[j] + k0, &Bs[j * 1024 + tid * 8]);
        __syncthreads();
        #pragma unroll
        for (int kk = 0; kk < 2; ++kk) {
            s16x8 bf[4];
            #pragma unroll
            for (int ni = 0; ni < 4; ++ni)
                bf[ni] = lds_frag(Bs, ni * 16 + r16, kk * 64 + cb0);
            #pragma unroll
            for (int mi = 0; mi < 4; ++mi) {
                s16x8 af = lds_frag(As, w * 64 + mi * 16 + r16, kk * 64 + cb0);
                #pragma unroll
                for (int ni = 0; ni < 4; ++ni)
                    acc[mi][ni] = __builtin_amdgcn_mfma_f32_16x16x32_bf16(af, bf[ni], acc[mi][ni], 0, 0, 0);
            }
        }
        __syncthreads();
    }

    ushort* eop = kc ? eo1 : eo0;
    #pragma unroll
    for (int mi = 0; mi < 4; ++mi) {
        #pragma unroll
        for (int j = 0; j < 4; ++j) {
            int p = mbase + w * 64 + mi * 16 + g4 * 4 + j;
            if (p < M) {
                int slot = slot_list[e * T_TOK + p];
                #pragma unroll
                for (int ni = 0; ni < 4; ++ni) {
                    int col = nbase + ni * 16 + r16;
                    eop[(size_t)slot * H_DIM + col] = f2bf(acc[mi][ni][j]);
                }
            }
        }
    }
}

// ---------------- combine: out[t] = sum_kc,k (eo[kc][slot]) + w·b3 ----------------
__global__ __launch_bounds__(256) void combine_kernel(
    const ushort* __restrict__ eo0, const ushort* __restrict__ eo1,
    const int* __restrict__ topi_packed,
    const float* __restrict__ wt_slot, const float* __restrict__ b3,
    float* __restrict__ out)
{
    const int i = blockIdx.x * 256 + threadIdx.x;     // over T*H/8
    const int t = i >> 7;
    const int c0 = (i & 127) * 8;
    const int pk = topi_packed[t];
    const int e0 = pk & 0xff, e1 = (pk >> 8) & 0xff;
    const float w0 = wt_slot[2 * t], w1 = wt_slot[2 * t + 1];
    s16x8 a0 = *(const s16x8*)(eo0 + (size_t)(2 * t) * H_DIM + c0);
    s16x8 b0 = *(const s16x8*)(eo0 + (size_t)(2 * t + 1) * H_DIM + c0);
    s16x8 a1 = *(const s16x8*)(eo1 + (size_t)(2 * t) * H_DIM + c0);
    s16x8 b1 = *(const s16x8*)(eo1 + (size_t)(2 * t + 1) * H_DIM + c0);
    const float4* p0 = (const float4*)(b3 + e0 * H_DIM + c0);
    const float4* p1 = (const float4*)(b3 + e1 * H_DIM + c0);
    float4 b0a = p0[0], b0b = p0[1];
    float4 b1a = p1[0], b1b = p1[1];
    float r[8];
    #pragma unroll
    for (int j = 0; j < 8; ++j)
        r[j] = (bf2f(a0[j]) + bf2f(a1[j])) + (bf2f(b0[j]) + bf2f(b1[j]));
    float4 r0, r1;
    r0.x = r[0] + w0 * b0a.x + w1 * b1a.x;
    r0.y = r[1] + w0 * b0a.y + w1 * b1a.y;
    r0.z = r[2] + w0 * b0a.z + w1 * b1a.z;
    r0.w = r[3] + w0 * b0a.w + w1 * b1a.w;
    r1.x = r[4] + w0 * b0b.x + w1 * b1b.x;
    r1.y = r[5] + w0 * b0b.y + w1 * b1b.y;
    r1.z = r[6] + w0 * b0b.z + w1 * b1b.z;
    r1.w = r[7] + w0 * b0b.w + w1 * b1b.w;
    float4* op = (float4*)(out + (size_t)t * H_DIM + c0);
    op[0] = r0;
    op[1] = r1;
}

extern "C" void kernel_launch(void* const* d_in, const int* in_sizes, int n_in,
                              void* d_out, int out_size, void* d_ws, size_t ws_size,
                              hipStream_t stream) {
    const float* x  = (const float*)d_in[0];
    const float* Wg = (const float*)d_in[1];
    const float* W1 = (const float*)d_in[2];
    const float* b1 = (const float*)d_in[3];
    const float* W2 = (const float*)d_in[4];
    const float* b2 = (const float*)d_in[5];
    const float* W3 = (const float*)d_in[6];
    const float* b3 = (const float*)d_in[7];
    float* out = (float*)d_out;

    char* ws = (char*)d_ws;
    // control block: 0..1 MB
    int*   cnt       = (int*)(ws);
    int*   tok_list  = (int*)(ws + 1024);
    int*   slot_list = (int*)(ws + 1024 + E_NUM * T_TOK * 4);
    float* wt_slot   = (float*)(ws + 1024 + 2 * E_NUM * T_TOK * 4);
    int*   topi      = (int*)(ws + 320 * 1024);
    // phase-1 (through up): xbf 1..9, w1bf 16..48, w2bf 48..80, hbuf 80..113.6
    ushort* xbf  = (ushort*)(ws + (size_t)1  * (1u << 20));
    ushort* w1bf = (ushort*)(ws + (size_t)16 * (1u << 20));
    ushort* w2bf = (ushort*)(ws + (size_t)48 * (1u << 20));
    ushort* hbuf = (ushort*)(ws + (size_t)80 * (1u << 20));
    // phase-2 (after up): eo planes in dead xbf/w1 region
    ushort* eo0 = (ushort*)(ws + (size_t)4  * (1u << 20));   //  4..20.8
    ushort* eo1 = (ushort*)(ws + (size_t)21 * (1u << 20));   // 21..37.8

    // W3 bf16: dedicated region above hbuf if workspace allows (converted
    // concurrently inside up's grid), else dead w1/w2 region converted after up.
    const bool bigws = ws_size >= ((size_t)147 << 20);
    ushort* w3bf = bigws ? (ushort*)(ws + (size_t)114 * (1u << 20))   // 114..147.6
                         : (ushort*)(ws + (size_t)40  * (1u << 20));  //  40..73.6 (dead w1/w2)

    cvtW_gate_kernel<<<CVT_BLOCKS + T_TOK / 4, 256, 0, stream>>>(
        W1, w1bf, W2, w2bf, x, Wg, topi, wt_slot, xbf);

    build_lists<<<E_NUM, 256, 0, stream>>>(topi, cnt, tok_list, slot_list);

    dim3 gup(DFF_D / 64, MAXJOBS64 + W3_ROWS);
    up_kernel<<<gup, 256, 0, stream>>>(xbf, w1bf, b1, w2bf, b2, cnt, tok_list,
                                       slot_list, wt_slot,
                                       bigws ? W3 : nullptr, w3bf, hbuf);

    if (!bigws)
        cvt_kernel<<<2048, 256, 0, stream>>>(W3, w3bf, E_NUM * H_DIM * DFF_D / 8);

    dim3 gdn((H_DIM / 64) * 2, MAXJOBS64);    // y over-provisioned; dead rows exit fast
    down_kernel<<<gdn, 128, 0, stream>>>(hbuf, w3bf, cnt, slot_list, eo0, eo1);

    combine_kernel<<<T_TOK * H_DIM / 8 / 256, 256, 0, stream>>>(eo0, eo1, topi, wt_slot, b3, out);
}

// Round 17
// 245.016 us; speedup vs baseline: 1.2285x; 1.0112x over previous
//
#include <hip/hip_runtime.h>
#include <hip/hip_bf16.h>

#define T_TOK 4096
#define H_DIM 1024
#define DFF_D 2048
#define E_NUM 8
#define K_TOP 2
#define MAXJOBS64 136
#define CVT_BLOCKS 2048
#define W3_ROWS 16     // leading blockIdx.y rows in up's grid convert W3 (dispatch first)

typedef __attribute__((ext_vector_type(8))) short s16x8;
typedef __attribute__((ext_vector_type(4))) float f32x4;

__device__ __forceinline__ ushort f2bf(float f) {
    unsigned u = __float_as_uint(f);
    u = (u + 0x7FFFu + ((u >> 16) & 1u)) >> 16;  // RNE
    return (ushort)u;
}

__device__ __forceinline__ float bf2f(short s) {
    return __uint_as_float(((unsigned)(ushort)s) << 16);
}

__device__ __forceinline__ void glds16(const ushort* g, ushort* l) {
    __builtin_amdgcn_global_load_lds(
        (const __attribute__((address_space(1))) unsigned*)g,
        (__attribute__((address_space(3))) unsigned*)l, 16, 0, 0);
}

// swizzled LDS fragment read: tile stored [rows][64] bf16 (128B rows),
// source staged with matching inverse swizzle on the global address.
__device__ __forceinline__ s16x8 lds_frag(const ushort* base, int row, int bytecol) {
    int byte = row * 128 + (bytecol ^ ((row & 7) << 4));
    return *(const s16x8*)((const char*)base + byte);
}

__device__ __forceinline__ void cvt8(const float* p, ushort* dst, size_t i) {
    float4 a = ((const float4*)(p + i * 8))[0];
    float4 b = ((const float4*)(p + i * 8))[1];
    union { ushort us[8]; uint4 q; } o;
    o.us[0] = f2bf(a.x); o.us[1] = f2bf(a.y); o.us[2] = f2bf(a.z); o.us[3] = f2bf(a.w);
    o.us[4] = f2bf(b.x); o.us[5] = f2bf(b.y); o.us[6] = f2bf(b.z); o.us[7] = f2bf(b.w);
    ((uint4*)dst)[i] = o.q;
}

// inline (e, mtile) derivation from cnt[], BM=64 granularity.
__device__ __forceinline__ bool job_from_y64(const int* cnt, int y, int& e, int& mbase, int& M) {
    int n = 0; mbase = -1;
    #pragma unroll
    for (int ee = 0; ee < E_NUM; ++ee) {
        int t = (cnt[ee] + 63) >> 6;
        if (mbase < 0 && y < n + t) { e = ee; mbase = (y - n) * 64; }
        n += t;
    }
    if (mbase < 0) return false;
    M = cnt[e];
    return true;
}

// inline (e, mtile) derivation from cnt[], BM=128 granularity (down).
__device__ __forceinline__ bool job_from_y128(const int* cnt, int y, int& e, int& mbase, int& M) {
    int n = 0; mbase = -1;
    #pragma unroll
    for (int ee = 0; ee < E_NUM; ++ee) {
        int t = (cnt[ee] + 127) >> 7;
        if (mbase < 0 && y < n + t) { e = ee; mbase = (y - n) * 128; }
        n += t;
    }
    if (mbase < 0) return false;
    M = cnt[e];
    return true;
}

// ---------------- fp32 -> bf16 bulk convert (W3 fallback path) ----------------
__global__ __launch_bounds__(256) void cvt_kernel(
    const float* __restrict__ in, ushort* __restrict__ out, int n8)
{
    int i = blockIdx.x * blockDim.x + threadIdx.x;
    const int stride = gridDim.x * blockDim.x;
    for (; i < n8; i += stride) cvt8(in, out, i);
}

// ---------------- fused: W1/W2 converts (blocks < CVT_BLOCKS) + gate ----------------
__global__ __launch_bounds__(256) void cvtW_gate_kernel(
    const float* __restrict__ W1, ushort* __restrict__ w1bf,
    const float* __restrict__ W2, ushort* __restrict__ w2bf,
    const float* __restrict__ x,  const float* __restrict__ Wg,
    int* __restrict__ topi_packed, float* __restrict__ wt_slot,
    ushort* __restrict__ xbf)
{
    if ((int)blockIdx.x < CVT_BLOCKS) {
        const int nW = E_NUM * DFF_D * H_DIM / 8;   // 2,097,152 chunks each
        int i = blockIdx.x * 256 + threadIdx.x;
        const int stride = CVT_BLOCKS * 256;
        for (; i < 2 * nW; i += stride) {
            if (i < nW) cvt8(W1, w1bf, i);
            else        cvt8(W2, w2bf, i - nW);
        }
        return;
    }
    // ---- gate path: 4 tokens per block ----
    const int t = (blockIdx.x - CVT_BLOCKS) * 4 + (threadIdx.x >> 6);
    const int lane = threadIdx.x & 63;
    const float* xr = x + (size_t)t * H_DIM;
    float xv[16];
    #pragma unroll
    for (int j = 0; j < 16; ++j) xv[j] = xr[j * 64 + lane];

    ushort* xo = xbf + (size_t)t * H_DIM;
    #pragma unroll
    for (int j = 0; j < 16; ++j) xo[j * 64 + lane] = f2bf(xv[j]);

    float score[E_NUM];
    #pragma unroll
    for (int e = 0; e < E_NUM; ++e) {
        const float* wr = Wg + e * H_DIM;
        float p = 0.f;
        #pragma unroll
        for (int j = 0; j < 16; ++j) p += xv[j] * wr[j * 64 + lane];
        #pragma unroll
        for (int s = 32; s >= 1; s >>= 1) p += __shfl_xor(p, s, 64);
        score[e] = p;
    }
    if (lane == 0) {
        int i0 = 0;
        #pragma unroll
        for (int e = 1; e < E_NUM; ++e) if (score[e] > score[i0]) i0 = e;
        int i1 = (i0 == 0) ? 1 : 0;
        #pragma unroll
        for (int e = 0; e < E_NUM; ++e)
            if (e != i0 && score[e] > score[i1]) i1 = e;
        float e1 = expf(score[i1] - score[i0]);
        float w0 = 1.f / (1.f + e1);
        float w1 = e1 / (1.f + e1);
        topi_packed[t] = i0 | (i1 << 8);
        wt_slot[t * K_TOP + 0] = w0;
        wt_slot[t * K_TOP + 1] = w1;
    }
}

// ---------------- per-expert token lists via LDS atomics ----------------
__global__ __launch_bounds__(256) void build_lists(
    const int* __restrict__ topi_packed,
    int* __restrict__ cnt, int* __restrict__ tok_list, int* __restrict__ slot_list)
{
    const int e = blockIdx.x;
    __shared__ int lcnt;
    if (threadIdx.x == 0) lcnt = 0;
    __syncthreads();
    for (int t = threadIdx.x; t < T_TOK; t += 256) {
        int pk = topi_packed[t];
        int i0 = pk & 0xff;
        int i1 = (pk >> 8) & 0xff;
        if (i0 == e) {
            int p = atomicAdd(&lcnt, 1);
            tok_list[e * T_TOK + p] = t;
            slot_list[e * T_TOK + p] = t * K_TOP + 0;
        }
        if (i1 == e) {
            int p = atomicAdd(&lcnt, 1);
            tok_list[e * T_TOK + p] = t;
            slot_list[e * T_TOK + p] = t * K_TOP + 1;
        }
    }
    __syncthreads();
    if (threadIdx.x == 0) cnt[e] = lcnt;
}

// ---------------- up: h = w * silu(xW1^T+b1) * (xW2^T+b2), 64x(64+64) tile ----------------
// r6-measured core (96.5 us). Leading y-rows (dispatched FIRST) convert W3
// concurrently so the convert streams under the GEMM's spare HBM bandwidth.
__global__ __launch_bounds__(256) void up_kernel(
    const ushort* __restrict__ xbf,
    const ushort* __restrict__ w1bf, const float* __restrict__ b1,
    const ushort* __restrict__ w2bf, const float* __restrict__ b2,
    const int* __restrict__ cnt, const int* __restrict__ tok_list,
    const int* __restrict__ slot_list, const float* __restrict__ wt_slot,
    const float* __restrict__ W3src, ushort* __restrict__ w3dst,
    ushort* __restrict__ h)
{
    if ((int)blockIdx.y < W3_ROWS) {
        if (W3src != nullptr) {
            const int nW3 = E_NUM * H_DIM * DFF_D / 8;   // 2,097,152 chunks
            int i = (blockIdx.y * gridDim.x + blockIdx.x) * 256 + threadIdx.x;
            const int stride = W3_ROWS * gridDim.x * 256;
            for (; i < nW3; i += stride) cvt8(W3src, w3dst, i);
        }
        return;
    }
    int e, mbase, M;
    if (!job_from_y64(cnt, blockIdx.y - W3_ROWS, e, mbase, M)) return;
    const int nbase = blockIdx.x * 64;
    const int tid = threadIdx.x;
    const int lane = tid & 63;
    const int w = tid >> 6;

    __shared__ ushort As[64 * 64];
    __shared__ ushort B1s[64 * 64];
    __shared__ ushort B2s[64 * 64];

    const ushort* srcA[2];
    const ushort* srcB1[2];
    const ushort* srcB2[2];
    #pragma unroll
    for (int j = 0; j < 2; ++j) {
        int o = j * 4096 + tid * 16;
        int r = o >> 7;
        int cb = (o & 127) ^ ((r & 7) << 4);
        int lpos = mbase + r; if (lpos > M - 1) lpos = M - 1;
        int tok = tok_list[e * T_TOK + lpos];
        srcA[j]  = xbf + (size_t)tok * H_DIM + (cb >> 1);
        srcB1[j] = w1bf + ((size_t)e * DFF_D + nbase + r) * H_DIM + (cb >> 1);
        srcB2[j] = w2bf + ((size_t)e * DFF_D + nbase + r) * H_DIM + (cb >> 1);
    }

    const f32x4 zero = {0.f, 0.f, 0.f, 0.f};
    f32x4 accg[4], accv[4];
    #pragma unroll
    for (int ni = 0; ni < 4; ++ni) { accg[ni] = zero; accv[ni] = zero; }

    const int r16 = lane & 15;
    const int g4  = lane >> 4;
    const int cb0 = g4 * 16;

    for (int k0 = 0; k0 < H_DIM; k0 += 64) {
        #pragma unroll
        for (int j = 0; j < 2; ++j) {
            glds16(srcA[j]  + k0, &As[j * 2048 + tid * 8]);
            glds16(srcB1[j] + k0, &B1s[j * 2048 + tid * 8]);
            glds16(srcB2[j] + k0, &B2s[j * 2048 + tid * 8]);
        }
        __syncthreads();
        #pragma unroll
        for (int kk = 0; kk < 2; ++kk) {
            s16x8 af = lds_frag(As, w * 16 + r16, kk * 64 + cb0);
            #pragma unroll
            for (int ni = 0; ni < 4; ++ni) {
                s16x8 bf1 = lds_frag(B1s, ni * 16 + r16, kk * 64 + cb0);
                s16x8 bf2 = lds_frag(B2s, ni * 16 + r16, kk * 64 + cb0);
                accg[ni] = __builtin_amdgcn_mfma_f32_16x16x32_bf16(af, bf1, accg[ni], 0, 0, 0);
                accv[ni] = __builtin_amdgcn_mfma_f32_16x16x32_bf16(af, bf2, accv[ni], 0, 0, 0);
            }
        }
        __syncthreads();
    }

    #pragma unroll
    for (int j = 0; j < 4; ++j) {
        int p = mbase + w * 16 + g4 * 4 + j;
        if (p < M) {
            int slot = slot_list[e * T_TOK + p];
            float wgt = wt_slot[slot];
            #pragma unroll
            for (int ni = 0; ni < 4; ++ni) {
                int col = nbase + ni * 16 + r16;
                float g = accg[ni][j] + b1[e * DFF_D + col];
                float v = accv[ni][j] + b2[e * DFF_D + col];
                float s = g / (1.f + __expf(-g));
                h[(size_t)slot * DFF_D + col] = f2bf(wgt * s * v);
            }
        }
    }
}

// ---------------- down: eo[kc][slot] = h @ W3^T partial (bf16, no atomics) ----------------
// r12-proven core: BM=128, BN=64, 128 thr = 2 waves (wave 64x64), 24KB LDS.
// Split-K=2: kc = blockIdx.x & 1.
__global__ __launch_bounds__(128) void down_kernel(
    const ushort* __restrict__ h,
    const ushort* __restrict__ w3bf,
    const int* __restrict__ cnt, const int* __restrict__ slot_list,
    ushort* __restrict__ eo0, ushort* __restrict__ eo1)
{
    int e, mbase, M;
    if (!job_from_y128(cnt, blockIdx.y, e, mbase, M)) return;
    const int nbase = (blockIdx.x >> 1) * 64;
    const int kc = blockIdx.x & 1;
    const int kbeg = kc * (DFF_D / 2);
    const int tid = threadIdx.x;
    const int lane = tid & 63;
    const int w = tid >> 6;     // 2 waves

    __shared__ ushort As[128 * 64];   // 16 KB
    __shared__ ushort Bs[64 * 64];    //  8 KB

    const ushort* srcA[8];
    #pragma unroll
    for (int j = 0; j < 8; ++j) {
        int o = j * 2048 + tid * 16;
        int r = o >> 7;
        int cb = (o & 127) ^ ((r & 7) << 4);
        int lpos = mbase + r; if (lpos > M - 1) lpos = M - 1;
        int slot = slot_list[e * T_TOK + lpos];
        srcA[j] = h + (size_t)slot * DFF_D + kbeg + (cb >> 1);
    }
    const ushort* srcB[4];
    #pragma unroll
    for (int j = 0; j < 4; ++j) {
        int o = j * 2048 + tid * 16;
        int r = o >> 7;
        int cb = (o & 127) ^ ((r & 7) << 4);
        srcB[j] = w3bf + ((size_t)e * H_DIM + nbase + r) * DFF_D + kbeg + (cb >> 1);
    }

    const f32x4 zero = {0.f, 0.f, 0.f, 0.f};
    f32x4 acc[4][4];
    #pragma unroll
    for (int mi = 0; mi < 4; ++mi)
        #pragma unroll
        for (int ni = 0; ni < 4; ++ni) acc[mi][ni] = zero;

    const int r16 = lane & 15;
    const int g4  = lane >> 4;
    const int cb0 = g4 * 16;

    for (int k0 = 0; k0 < DFF_D / 2; k0 += 64) {
        #pragma unroll
        for (int j = 0; j < 8; ++j)
            glds16(srcA[j] + k0, &As[j * 1024 + tid * 8]);
        #pragma unroll
        for (int j = 0; j < 4; ++j)
            glds16(srcB[j] + k0, &Bs[j * 1024 + tid * 8]);
        __syncthreads();
        #pragma unroll
        for (int kk = 0; kk < 2; ++kk) {
            s16x8 bf[4];
            #pragma unroll
            for (int ni = 0; ni < 4; ++ni)
                bf[ni] = lds_frag(Bs, ni * 16 + r16, kk * 64 + cb0);
            #pragma unroll
            for (int mi = 0; mi < 4; ++mi) {
                s16x8 af = lds_frag(As, w * 64 + mi * 16 + r16, kk * 64 + cb0);
                #pragma unroll
                for (int ni = 0; ni < 4; ++ni)
                    acc[mi][ni] = __builtin_amdgcn_mfma_f32_16x16x32_bf16(af, bf[ni], acc[mi][ni], 0, 0, 0);
            }
        }
        __syncthreads();
    }

    ushort* eop = kc ? eo1 : eo0;
    #pragma unroll
    for (int mi = 0; mi < 4; ++mi) {
        #pragma unroll
        for (int j = 0; j < 4; ++j) {
            int p = mbase + w * 64 + mi * 16 + g4 * 4 + j;
            if (p < M) {
                int slot = slot_list[e * T_TOK + p];
                #pragma unroll
                for (int ni = 0; ni < 4; ++ni) {
                    int col = nbase + ni * 16 + r16;
                    eop[(size_t)slot * H_DIM + col] = f2bf(acc[mi][ni][j]);
                }
            }
        }
    }
}

// ---------------- combine: out[t] = sum_kc,k (eo[kc][slot]) + w·b3 ----------------
__global__ __launch_bounds__(256) void combine_kernel(
    const ushort* __restrict__ eo0, const ushort* __restrict__ eo1,
    const int* __restrict__ topi_packed,
    const float* __restrict__ wt_slot, const float* __restrict__ b3,
    float* __restrict__ out)
{
    const int i = blockIdx.x * 256 + threadIdx.x;     // over T*H/8
    const int t = i >> 7;
    const int c0 = (i & 127) * 8;
    const int pk = topi_packed[t];
    const int e0 = pk & 0xff, e1 = (pk >> 8) & 0xff;
    const float w0 = wt_slot[2 * t], w1 = wt_slot[2 * t + 1];
    s16x8 a0 = *(const s16x8*)(eo0 + (size_t)(2 * t) * H_DIM + c0);
    s16x8 b0 = *(const s16x8*)(eo0 + (size_t)(2 * t + 1) * H_DIM + c0);
    s16x8 a1 = *(const s16x8*)(eo1 + (size_t)(2 * t) * H_DIM + c0);
    s16x8 b1 = *(const s16x8*)(eo1 + (size_t)(2 * t + 1) * H_DIM + c0);
    const float4* p0 = (const float4*)(b3 + e0 * H_DIM + c0);
    const float4* p1 = (const float4*)(b3 + e1 * H_DIM + c0);
    float4 b0a = p0[0], b0b = p0[1];
    float4 b1a = p1[0], b1b = p1[1];
    float r[8];
    #pragma unroll
    for (int j = 0; j < 8; ++j)
        r[j] = (bf2f(a0[j]) + bf2f(a1[j])) + (bf2f(b0[j]) + bf2f(b1[j]));
    float4 r0, r1;
    r0.x = r[0] + w0 * b0a.x + w1 * b1a.x;
    r0.y = r[1] + w0 * b0a.y + w1 * b1a.y;
    r0.z = r[2] + w0 * b0a.z + w1 * b1a.z;
    r0.w = r[3] + w0 * b0a.w + w1 * b1a.w;
    r1.x = r[4] + w0 * b0b.x + w1 * b1b.x;
    r1.y = r[5] + w0 * b0b.y + w1 * b1b.y;
    r1.z = r[6] + w0 * b0b.z + w1 * b1b.z;
    r1.w = r[7] + w0 * b0b.w + w1 * b1b.w;
    float4* op = (float4*)(out + (size_t)t * H_DIM + c0);
    op[0] = r0;
    op[1] = r1;
}

extern "C" void kernel_launch(void* const* d_in, const int* in_sizes, int n_in,
                              void* d_out, int out_size, void* d_ws, size_t ws_size,
                              hipStream_t stream) {
    const float* x  = (const float*)d_in[0];
    const float* Wg = (const float*)d_in[1];
    const float* W1 = (const float*)d_in[2];
    const float* b1 = (const float*)d_in[3];
    const float* W2 = (const float*)d_in[4];
    const float* b2 = (const float*)d_in[5];
    const float* W3 = (const float*)d_in[6];
    const float* b3 = (const float*)d_in[7];
    float* out = (float*)d_out;

    char* ws = (char*)d_ws;
    // control block: 0..1 MB
    int*   cnt       = (int*)(ws);
    int*   tok_list  = (int*)(ws + 1024);
    int*   slot_list = (int*)(ws + 1024 + E_NUM * T_TOK * 4);
    float* wt_slot   = (float*)(ws + 1024 + 2 * E_NUM * T_TOK * 4);
    int*   topi      = (int*)(ws + 320 * 1024);
    // phase-1 (through up): xbf 1..9, w1bf 16..48, w2bf 48..80, hbuf 80..113.6
    ushort* xbf  = (ushort*)(ws + (size_t)1  * (1u << 20));
    ushort* w1bf = (ushort*)(ws + (size_t)16 * (1u << 20));
    ushort* w2bf = (ushort*)(ws + (size_t)48 * (1u << 20));
    ushort* hbuf = (ushort*)(ws + (size_t)80 * (1u << 20));
    // phase-2 (after up): eo planes in dead xbf/w1 region
    ushort* eo0 = (ushort*)(ws + (size_t)4  * (1u << 20));   //  4..20.8
    ushort* eo1 = (ushort*)(ws + (size_t)21 * (1u << 20));   // 21..37.8

    // W3 bf16: dedicated region above hbuf if workspace allows (converted
    // concurrently inside up's grid), else dead w1/w2 region converted after up.
    const bool bigws = ws_size >= ((size_t)147 << 20);
    ushort* w3bf = bigws ? (ushort*)(ws + (size_t)114 * (1u << 20))   // 114..147.6
                         : (ushort*)(ws + (size_t)40  * (1u << 20));  //  40..73.6 (dead w1/w2)

    cvtW_gate_kernel<<<CVT_BLOCKS + T_TOK / 4, 256, 0, stream>>>(
        W1, w1bf, W2, w2bf, x, Wg, topi, wt_slot, xbf);

    build_lists<<<E_NUM, 256, 0, stream>>>(topi, cnt, tok_list, slot_list);

    dim3 gup(DFF_D / 64, MAXJOBS64 + W3_ROWS);
    up_kernel<<<gup, 256, 0, stream>>>(xbf, w1bf, b1, w2bf, b2, cnt, tok_list,
                                       slot_list, wt_slot,
                                       bigws ? W3 : nullptr, w3bf, hbuf);

    if (!bigws)
        cvt_kernel<<<2048, 256, 0, stream>>>(W3, w3bf, E_NUM * H_DIM * DFF_D / 8);

    dim3 gdn((H_DIM / 64) * 2, MAXJOBS64);    // y over-provisioned; dead rows exit fast
    down_kernel<<<gdn, 128, 0, stream>>>(hbuf, w3bf, cnt, slot_list, eo0, eo1);

    combine_kernel<<<T_TOK * H_DIM / 8 / 256, 256, 0, stream>>>(eo0, eo1, topi, wt_slot, b3, out);
}